// Round 1
// baseline (381.658 us; speedup 1.0000x reference)
//
#include <hip/hip_runtime.h>
#include <hip/hip_bf16.h>

// GCN x3 + FC on a fixed random graph.  (R7: revert to R5 pull-CSR; R6's
// edge-centric LDS agg died on occupancy: 132KB LDS -> 1 block/CU -> 0.8TB/s.)
//   1. Bucket-partition CSR build: hist -> scan -> packed partition
//      (src|dl<<18) -> per-bucket build (LDS atomics, coalesced I/O) with
//      fused prescale y0 = dinv*x.
//   2. Pull aggregation over pre-scaled features y = dinv*h:
//      out[v] = dinv[v]*(sum y[s] + y[v]).  Transform fused into agg epilogue
//      via per-block LDS staging (aggt1: 8->16, aggt2: 16->32).
//   3. y2 stored bf16 (64B rows): halves agg3's random-gather sectors
//      (R5 profile implies 64B fetch granularity: agg<2>/agg<4> cheaper than
//      agg<8> despite equal edge count).
//   4. t3fc: per-thread full-node GEMMs (R8).  R7's 2x4 register tile read
//      24B LDS per 16 FLOP = 1.5 B/FLOP vs 0.33 machine balance -> LDS-BW
//      bound at ~78us.  Now: W3/Wf via thread-uniform indices -> s_load ->
//      SGPR operand of v_fma (zero LDS); activations in a private per-thread
//      LDS row (pitch 65 -> conflict-free); 64 reg accumulators, j fully
//      unrolled.  0.06 B/FLOP -> VALU-bound (~20.5us floor).

#define NB   256     // dst buckets
#define NPB  1024    // nodes per bucket (N = NB*NPB)
#define TILE 4096    // edges per partition tile
#define SRCMASK 0x3FFFFu

__device__ __forceinline__ float bf_lo(unsigned u) { return __uint_as_float(u << 16); }
__device__ __forceinline__ float bf_hi(unsigned u) { return __uint_as_float(u & 0xFFFF0000u); }
__device__ __forceinline__ unsigned bf_rne(float f) {   // fp32 -> bf16 bits (RNE)
    unsigned b = __float_as_uint(f);
    return (b + 0x7FFFu + ((b >> 16) & 1u)) >> 16;
}

// ---- P1: global bucket histogram -------------------------------------------
__global__ void hist_kernel(const int* __restrict__ dst, int* __restrict__ ghist,
                            int E, int shift) {
    __shared__ int h[NB];
    int tid = threadIdx.x;
    h[tid] = 0;
    __syncthreads();
    int base = blockIdx.x * TILE;
    int cnt = min(TILE, E - base);
    for (int i = tid; i < cnt; i += 256)
        atomicAdd(&h[dst[base + i] >> shift], 1);
    __syncthreads();
    int v = h[tid];
    if (v) atomicAdd(&ghist[tid], v);
}

// ---- P2: scan bucket counts -> bbase[NB+1], init gcursor -------------------
__global__ void bscan_kernel(const int* __restrict__ ghist, int* __restrict__ bbase,
                             int* __restrict__ gcursor) {
    __shared__ int sh[NB];
    int tid = threadIdx.x;
    int v = ghist[tid];
    sh[tid] = v;
    __syncthreads();
    for (int o = 1; o < NB; o <<= 1) {
        int t = (tid >= o) ? sh[tid - o] : 0;
        __syncthreads();
        sh[tid] += t;
        __syncthreads();
    }
    int incl = sh[tid];
    bbase[tid] = incl - v;
    gcursor[tid] = incl - v;
    if (tid == NB - 1) bbase[NB] = incl;
}

// ---- P3: partition edges into bucket-contiguous packed stream --------------
__global__ void __launch_bounds__(256)
partition_kernel(const int* __restrict__ src, const int* __restrict__ dst,
                 int* __restrict__ gcursor, unsigned int* __restrict__ bedge,
                 int E, int shift, int mask) {
    __shared__ int h[NB], st[NB], gp[NB];
    __shared__ unsigned short rk[TILE];
    __shared__ int sd[TILE];
    __shared__ int ss[TILE];
    int tid = threadIdx.x;
    h[tid] = 0;
    __syncthreads();
    int base = blockIdx.x * TILE;
    int cnt = min(TILE, E - base);
    for (int i = tid; i < cnt; i += 256)
        rk[i] = (unsigned short)atomicAdd(&h[dst[base + i] >> shift], 1);
    __syncthreads();
    int hv = h[tid];
    st[tid] = hv;
    __syncthreads();
    for (int o = 1; o < NB; o <<= 1) {
        int t = (tid >= o) ? st[tid - o] : 0;
        __syncthreads();
        st[tid] += t;
        __syncthreads();
    }
    st[tid] -= hv;
    gp[tid] = hv ? atomicAdd(&gcursor[tid], hv) : 0;
    __syncthreads();
    for (int i = tid; i < cnt; i += 256) {
        int d = dst[base + i];
        int b = d >> shift;
        int pos = st[b] + rk[i];
        sd[pos] = d;
        ss[pos] = src[base + i];
    }
    __syncthreads();
    for (int i = tid; i < cnt; i += 256) {
        int d = sd[i];
        int b = d >> shift;
        int g = gp[b] + (i - st[b]);
        bedge[g] = (unsigned int)ss[i] | ((unsigned int)(d & mask) << 18);
    }
}

// ---- P4: per-bucket CSR build + fused prescale -----------------------------
__global__ void __launch_bounds__(256)
build_kernel(const int* __restrict__ bbase, const unsigned int* __restrict__ bedge,
             const float* __restrict__ x,
             int* __restrict__ off, float* __restrict__ dinv, int* __restrict__ adj,
             float* __restrict__ y0) {
    __shared__ int deg1[NPB];
    __shared__ int cur[NPB];
    __shared__ int bs[256];
    int tid = threadIdx.x;
    int b = blockIdx.x;
    int s = bbase[b], e = bbase[b + 1];
    int base = tid * 4;
#pragma unroll
    for (int i = 0; i < 4; i++) deg1[base + i] = 0;
    __syncthreads();
    for (int i = s + tid; i < e; i += 256)
        atomicAdd(&deg1[bedge[i] >> 18], 1);
    __syncthreads();
    int d0 = deg1[base], d1 = deg1[base + 1], d2 = deg1[base + 2], d3 = deg1[base + 3];
    int th = d0 + d1 + d2 + d3;
    bs[tid] = th;
    __syncthreads();
    for (int o = 1; o < 256; o <<= 1) {
        int t = (tid >= o) ? bs[tid - o] : 0;
        __syncthreads();
        bs[tid] += t;
        __syncthreads();
    }
    int run = s + bs[tid] - th;
    int vb = b * NPB + base;
    off[vb]     = run; cur[base]     = run; dinv[vb]     = rsqrtf((float)(d0 + 1)); run += d0;
    off[vb + 1] = run; cur[base + 1] = run; dinv[vb + 1] = rsqrtf((float)(d1 + 1)); run += d1;
    off[vb + 2] = run; cur[base + 2] = run; dinv[vb + 2] = rsqrtf((float)(d2 + 1)); run += d2;
    off[vb + 3] = run; cur[base + 3] = run; dinv[vb + 3] = rsqrtf((float)(d3 + 1)); run += d3;
    if (b == NB - 1 && tid == 255) off[NB * NPB] = e;   // sentinel off[N] = E
    __syncthreads();
    for (int i = s + tid; i < e; i += 256) {
        unsigned int pk = bedge[i];
        int p = atomicAdd(&cur[pk >> 18], 1);
        adj[p] = (int)(pk & SRCMASK);
    }
    // fused prescale: y0[v] = dinv[v] * x[v]  (bucket rows, coalesced)
    for (int i = tid; i < NPB * 2; i += 256) {
        int v = i >> 1;
        float dv = rsqrtf((float)(deg1[v] + 1));
        float4 t = ((const float4*)x)[(size_t)b * NPB * 2 + i];
        t.x *= dv; t.y *= dv; t.z *= dv; t.w *= dv;
        ((float4*)y0)[(size_t)b * NPB * 2 + i] = t;
    }
}

// ---- Fused agg(8-dim) + transform 8->16 ------------------------------------
// gather: 2 lanes/node; epilogue: a1 = dinv*(sum+self) staged in LDS, then
// y1[v] = dinv[v]*relu(a1 @ W1 + b1).
__global__ void __launch_bounds__(256)
aggt1_kernel(const float* __restrict__ y0, const int* __restrict__ off,
             const int* __restrict__ adj, const float* __restrict__ dinv,
             const float* __restrict__ W1, const float* __restrict__ b1,
             float* __restrict__ y1) {
    __shared__ float Ws[8 * 16];
    __shared__ float bsh[16];
    __shared__ float sh[128][9];
    const int tid = threadIdx.x;
    if (tid < 128) Ws[tid] = W1[tid];
    if (tid < 16) bsh[tid] = b1[tid];
    const int vbase = blockIdx.x * 128;
    const int vl = tid >> 1, c = tid & 1;
    const int vg = vbase + vl;
    const float4* y4 = (const float4*)y0;
    int beg = off[vg];
    int end = off[vg + 1];
    float4 a0 = y4[(size_t)vg * 2 + c];   // self
    float4 a1, a2, a3;
    a1.x = a1.y = a1.z = a1.w = 0.f;
    a2.x = a2.y = a2.z = a2.w = 0.f;
    a3.x = a3.y = a3.z = a3.w = 0.f;
    int e = beg;
    for (; e + 4 <= end; e += 4) {
        int s0 = adj[e], s1 = adj[e + 1], s2 = adj[e + 2], s3 = adj[e + 3];
        float4 x0 = y4[(size_t)s0 * 2 + c];
        float4 x1 = y4[(size_t)s1 * 2 + c];
        float4 x2 = y4[(size_t)s2 * 2 + c];
        float4 x3 = y4[(size_t)s3 * 2 + c];
        a0.x += x0.x; a0.y += x0.y; a0.z += x0.z; a0.w += x0.w;
        a1.x += x1.x; a1.y += x1.y; a1.z += x1.z; a1.w += x1.w;
        a2.x += x2.x; a2.y += x2.y; a2.z += x2.z; a2.w += x2.w;
        a3.x += x3.x; a3.y += x3.y; a3.z += x3.z; a3.w += x3.w;
    }
    for (; e < end; e++) {
        float4 xs = y4[(size_t)adj[e] * 2 + c];
        a1.x += xs.x; a1.y += xs.y; a1.z += xs.z; a1.w += xs.w;
    }
    float dv = dinv[vg];
    sh[vl][c * 4 + 0] = ((a0.x + a1.x) + (a2.x + a3.x)) * dv;
    sh[vl][c * 4 + 1] = ((a0.y + a1.y) + (a2.y + a3.y)) * dv;
    sh[vl][c * 4 + 2] = ((a0.z + a1.z) + (a2.z + a3.z)) * dv;
    sh[vl][c * 4 + 3] = ((a0.w + a1.w) + (a2.w + a3.w)) * dv;
    __syncthreads();
    // transform: thread -> (node nl, half hf), 8 outputs
    const int nl = tid & 127, hf = tid >> 7, j0 = hf * 8;
    float in0 = sh[nl][0], in1 = sh[nl][1], in2 = sh[nl][2], in3 = sh[nl][3];
    float in4 = sh[nl][4], in5 = sh[nl][5], in6 = sh[nl][6], in7 = sh[nl][7];
    float dn = dinv[vbase + nl];
    float o[8];
#pragma unroll
    for (int jj = 0; jj < 8; jj++) {
        int j = j0 + jj;
        float acc = bsh[j];
        acc += in0 * Ws[0 * 16 + j]; acc += in1 * Ws[1 * 16 + j];
        acc += in2 * Ws[2 * 16 + j]; acc += in3 * Ws[3 * 16 + j];
        acc += in4 * Ws[4 * 16 + j]; acc += in5 * Ws[5 * 16 + j];
        acc += in6 * Ws[6 * 16 + j]; acc += in7 * Ws[7 * 16 + j];
        o[jj] = dn * fmaxf(acc, 0.f);
    }
    float4* out4 = (float4*)(y1 + (size_t)(vbase + nl) * 16 + j0);
    float4 t0; t0.x = o[0]; t0.y = o[1]; t0.z = o[2]; t0.w = o[3];
    float4 t1; t1.x = o[4]; t1.y = o[5]; t1.z = o[6]; t1.w = o[7];
    out4[0] = t0; out4[1] = t1;
}

// ---- Fused agg(16-dim) + transform 16->32, bf16 output ---------------------
__global__ void __launch_bounds__(256)
aggt2_kernel(const float* __restrict__ y1, const int* __restrict__ off,
             const int* __restrict__ adj, const float* __restrict__ dinv,
             const float* __restrict__ W2, const float* __restrict__ b2,
             unsigned int* __restrict__ y2b) {
    __shared__ float Ws[16 * 32];
    __shared__ float bsh[32];
    __shared__ float sh[64][17];
    const int tid = threadIdx.x;
    for (int i = tid; i < 16 * 32; i += 256) Ws[i] = W2[i];
    if (tid < 32) bsh[tid] = b2[tid];
    const int vbase = blockIdx.x * 64;
    const int vl = tid >> 2, c = tid & 3;
    const int vg = vbase + vl;
    const float4* y4 = (const float4*)y1;
    int beg = off[vg];
    int end = off[vg + 1];
    float4 a0 = y4[(size_t)vg * 4 + c];   // self
    float4 a1, a2, a3;
    a1.x = a1.y = a1.z = a1.w = 0.f;
    a2.x = a2.y = a2.z = a2.w = 0.f;
    a3.x = a3.y = a3.z = a3.w = 0.f;
    int e = beg;
    for (; e + 4 <= end; e += 4) {
        int s0 = adj[e], s1 = adj[e + 1], s2 = adj[e + 2], s3 = adj[e + 3];
        float4 x0 = y4[(size_t)s0 * 4 + c];
        float4 x1 = y4[(size_t)s1 * 4 + c];
        float4 x2 = y4[(size_t)s2 * 4 + c];
        float4 x3 = y4[(size_t)s3 * 4 + c];
        a0.x += x0.x; a0.y += x0.y; a0.z += x0.z; a0.w += x0.w;
        a1.x += x1.x; a1.y += x1.y; a1.z += x1.z; a1.w += x1.w;
        a2.x += x2.x; a2.y += x2.y; a2.z += x2.z; a2.w += x2.w;
        a3.x += x3.x; a3.y += x3.y; a3.z += x3.z; a3.w += x3.w;
    }
    for (; e < end; e++) {
        float4 xs = y4[(size_t)adj[e] * 4 + c];
        a1.x += xs.x; a1.y += xs.y; a1.z += xs.z; a1.w += xs.w;
    }
    float dv = dinv[vg];
    sh[vl][c * 4 + 0] = ((a0.x + a1.x) + (a2.x + a3.x)) * dv;
    sh[vl][c * 4 + 1] = ((a0.y + a1.y) + (a2.y + a3.y)) * dv;
    sh[vl][c * 4 + 2] = ((a0.z + a1.z) + (a2.z + a3.z)) * dv;
    sh[vl][c * 4 + 3] = ((a0.w + a1.w) + (a2.w + a3.w)) * dv;
    __syncthreads();
    // transform: thread -> (node nl, quarter q), 8 outputs, pack bf16
    const int nl = tid & 63, q = tid >> 6, j0 = q * 8;
    float in[16];
#pragma unroll
    for (int k = 0; k < 16; k++) in[k] = sh[nl][k];
    float dn = dinv[vbase + nl];
    unsigned r[8];
#pragma unroll
    for (int jj = 0; jj < 8; jj++) {
        int j = j0 + jj;
        float acc = bsh[j];
#pragma unroll
        for (int k = 0; k < 16; k++) acc += in[k] * Ws[k * 32 + j];
        r[jj] = bf_rne(dn * fmaxf(acc, 0.f));
    }
    uint4 pk;
    pk.x = r[0] | (r[1] << 16); pk.y = r[2] | (r[3] << 16);
    pk.z = r[4] | (r[5] << 16); pk.w = r[6] | (r[7] << 16);
    ((uint4*)y2b)[(size_t)(vbase + nl) * 4 + q] = pk;
}

// ---- agg(32-dim, bf16 rows) -> fp32 a3 -------------------------------------
// 4 lanes/node, each lane one uint4 (8 bf16) chunk; 2-way unrolled.
__global__ void __launch_bounds__(256)
agg_bf16_kernel(const unsigned int* __restrict__ y2b, const int* __restrict__ off,
                const int* __restrict__ adj, const float* __restrict__ dinv,
                float* __restrict__ a3out, int n) {
    int t = blockIdx.x * 256 + threadIdx.x;
    int v = t >> 2, c = t & 3;
    if (v >= n) return;
    const uint4* yb = (const uint4*)y2b;
    uint4 us = yb[(size_t)v * 4 + c];   // self
    float p0 = bf_lo(us.x), p1 = bf_hi(us.x), p2 = bf_lo(us.y), p3 = bf_hi(us.y);
    float p4 = bf_lo(us.z), p5 = bf_hi(us.z), p6 = bf_lo(us.w), p7 = bf_hi(us.w);
    float q0 = 0, q1 = 0, q2 = 0, q3 = 0, q4 = 0, q5 = 0, q6 = 0, q7 = 0;
    int beg = off[v], end = off[v + 1];
    int e = beg;
    for (; e + 2 <= end; e += 2) {
        int s0 = adj[e], s1 = adj[e + 1];
        uint4 u0 = yb[(size_t)s0 * 4 + c];
        uint4 u1 = yb[(size_t)s1 * 4 + c];
        p0 += bf_lo(u0.x); p1 += bf_hi(u0.x); p2 += bf_lo(u0.y); p3 += bf_hi(u0.y);
        p4 += bf_lo(u0.z); p5 += bf_hi(u0.z); p6 += bf_lo(u0.w); p7 += bf_hi(u0.w);
        q0 += bf_lo(u1.x); q1 += bf_hi(u1.x); q2 += bf_lo(u1.y); q3 += bf_hi(u1.y);
        q4 += bf_lo(u1.z); q5 += bf_hi(u1.z); q6 += bf_lo(u1.w); q7 += bf_hi(u1.w);
    }
    if (e < end) {
        uint4 u0 = yb[(size_t)adj[e] * 4 + c];
        p0 += bf_lo(u0.x); p1 += bf_hi(u0.x); p2 += bf_lo(u0.y); p3 += bf_hi(u0.y);
        p4 += bf_lo(u0.z); p5 += bf_hi(u0.z); p6 += bf_lo(u0.w); p7 += bf_hi(u0.w);
    }
    float dv = dinv[v];
    float4 o0, o1;
    o0.x = (p0 + q0) * dv; o0.y = (p1 + q1) * dv; o0.z = (p2 + q2) * dv; o0.w = (p3 + q3) * dv;
    o1.x = (p4 + q4) * dv; o1.y = (p5 + q5) * dv; o1.z = (p6 + q6) * dv; o1.w = (p7 + q7) * dv;
    float4* out4 = (float4*)a3out;
    out4[(size_t)v * 8 + c * 2]     = o0;
    out4[(size_t)v * 8 + c * 2 + 1] = o1;
}

// ---- Fused layer-3 transform + FC (per-thread full node, SGPR weights) -----
// R8: one thread = one node.  W3/Wf read with thread-uniform indices ->
// backend scalarizes to s_load -> weights ride the SGPR operand of v_fma
// (zero LDS, zero VGPR cost).  The runtime-k activation operand lives in a
// PRIVATE per-thread LDS row (pitch 65: bank=(tid+k)%32, 2-way = free,
// no cross-thread sharing -> no barriers).  64 fp32 reg accumulators,
// j-loop fully unrolled (static indices, no scratch).
// LDS traffic: 192 B32 ops / 12288 FLOP/node = 0.06 B/FLOP (machine balance
// 0.33) -> VALU-bound, ~20.5us floor vs R7's LDS-bound 78us.
#define T3_THREADS 128
#define T3_PITCH   65

__global__ void __launch_bounds__(T3_THREADS)
t3fc_kernel(const float* __restrict__ in,
            const float* __restrict__ W3, const float* __restrict__ b3,
            const float* __restrict__ Wf, const float* __restrict__ bf,
            float* __restrict__ out, int n) {
    __shared__ float row[T3_THREADS * T3_PITCH];   // 33.3 KB -> 4 blocks/CU
    const int tid = threadIdx.x;
    const int v = blockIdx.x * T3_THREADS + tid;
    float* my = row + tid * T3_PITCH;

    // stage this node's 32 inputs into its private LDS row
    const float4* g = (const float4*)(in + (size_t)v * 32);
#pragma unroll
    for (int c = 0; c < 8; c++) {
        float4 t = g[c];
        my[c * 4 + 0] = t.x; my[c * 4 + 1] = t.y;
        my[c * 4 + 2] = t.z; my[c * 4 + 3] = t.w;
    }

    float acc[64];
    // GEMM1: acc[j] = b3[j] + sum_k x[k]*W3[k][j]   (W3 row k via s_load)
#pragma unroll
    for (int j = 0; j < 64; j++) acc[j] = b3[j];
    for (int k = 0; k < 32; k++) {
        float xv = my[k];                       // 1 ds_read_b32 per 64 FMA
        const float* wr = W3 + k * 64;          // uniform address
#pragma unroll
        for (int j = 0; j < 64; j++) acc[j] = fmaf(xv, wr[j], acc[j]);
    }
    // relu -> private LDS row (t becomes the runtime-k operand of GEMM2)
#pragma unroll
    for (int j = 0; j < 64; j++) my[j] = fmaxf(acc[j], 0.f);

    // GEMM2: acc[j] = bf[j] + sum_k t[k]*Wf[k][j]
#pragma unroll
    for (int j = 0; j < 64; j++) acc[j] = bf[j];
    for (int k = 0; k < 64; k++) {
        float xv = my[k];
        const float* wr = Wf + k * 64;
#pragma unroll
        for (int j = 0; j < 64; j++) acc[j] = fmaf(xv, wr[j], acc[j]);
    }

    float4* o = (float4*)(out + (size_t)v * 64);
#pragma unroll
    for (int c = 0; c < 16; c++) {
        float4 t;
        t.x = acc[c * 4 + 0]; t.y = acc[c * 4 + 1];
        t.z = acc[c * 4 + 2]; t.w = acc[c * 4 + 3];
        o[c] = t;
    }
}

extern "C" void kernel_launch(void* const* d_in, const int* in_sizes, int n_in,
                              void* d_out, int out_size, void* d_ws, size_t ws_size,
                              hipStream_t stream) {
    const float* x  = (const float*)d_in[0];
    const float* W1 = (const float*)d_in[1];
    const float* b1 = (const float*)d_in[2];
    const float* W2 = (const float*)d_in[3];
    const float* b2 = (const float*)d_in[4];
    const float* W3 = (const float*)d_in[5];
    const float* b3 = (const float*)d_in[6];
    const float* Wf = (const float*)d_in[7];
    const float* bf = (const float*)d_in[8];
    const int*   ei = (const int*)d_in[9];

    const int N = in_sizes[0] / 8;   // 262144
    const int E = in_sizes[9] / 2;   // 2097152
    const int* srcv = ei;
    const int* dstv = ei + E;
    const int shift = 10;            // log2(NPB)

    // Workspace layout (16B-aligned chunks)
    char* p = (char*)d_ws;
    auto take = [&p](size_t bytes) { char* q = p; p += (bytes + 63) & ~size_t(63); return q; };
    int*   off   = (int*)take((size_t)(N + 16) * 4);
    float* dinv  = (float*)take((size_t)N * 4);
    int*   adj   = (int*)take((size_t)E * 4);
    int*   ghist = (int*)take(NB * 4);
    int*   bbase = (int*)take((NB + 1) * 4);
    int*   gcur  = (int*)take(NB * 4);
    float* bufA  = (float*)take((size_t)N * 32 * 4);   // y0 [0,8MB) then a3 (33MB)
    float* y1    = (float*)take((size_t)N * 16 * 4);   // 16MB
    char*  regX  = take((size_t)N * 32 * 2);           // 16MB: bedge (8MB) then y2b
    unsigned int* bedge = (unsigned int*)regX;
    unsigned int* y2b   = (unsigned int*)regX;
    float* y0 = bufA;

    hipMemsetAsync(ghist, 0, NB * 4, stream);

    int nt = (E + TILE - 1) / TILE;  // 512 tiles
    hist_kernel<<<nt, 256, 0, stream>>>(dstv, ghist, E, shift);
    bscan_kernel<<<1, NB, 0, stream>>>(ghist, bbase, gcur);
    partition_kernel<<<nt, 256, 0, stream>>>(srcv, dstv, gcur, bedge, E, shift, NPB - 1);
    build_kernel<<<NB, 256, 0, stream>>>(bbase, bedge, x, off, dinv, adj, y0);

    // L1: agg(y0) + transform 8->16 -> y1
    aggt1_kernel<<<N / 128, 256, 0, stream>>>(y0, off, adj, dinv, W1, b1, y1);
    // L2: agg(y1) + transform 16->32 -> y2b (bf16; overwrites dead bedge)
    aggt2_kernel<<<N / 64, 256, 0, stream>>>(y1, off, adj, dinv, W2, b2, y2b);
    // L3: agg(y2b) -> a3 (bufA; y0 dead), then fused transform+FC -> out
    agg_bf16_kernel<<<(N * 4) / 256, 256, 0, stream>>>(y2b, off, adj, dinv, bufA, N);
    t3fc_kernel<<<N / T3_THREADS, T3_THREADS, 0, stream>>>(bufA, W3, b3, Wf, bf, (float*)d_out, N);
}

// Round 2
// 338.120 us; speedup vs baseline: 1.1288x; 1.1288x over previous
//
#include <hip/hip_runtime.h>
#include <hip/hip_bf16.h>

// GCN x3 + FC on a fixed random graph.  (R7: revert to R5 pull-CSR; R6's
// edge-centric LDS agg died on occupancy: 132KB LDS -> 1 block/CU -> 0.8TB/s.)
//   1. Bucket-partition CSR build: hist -> scan -> packed partition
//      (src|dl<<18) -> per-bucket build (LDS atomics, coalesced I/O) with
//      fused prescale y0 = dinv*x.
//   2. Pull aggregation over pre-scaled features y = dinv*h:
//      out[v] = dinv[v]*(sum y[s] + y[v]).  Transform fused into agg epilogue
//      via per-block LDS staging (aggt1: 8->16, aggt2: 16->32).
//   3. y2 stored bf16 (64B rows): halves agg3's random-gather sectors.
//   4. t3fc (R9): block-cooperative GEMM, 2-nodes x 8-cols register tile.
//      R7's 2x4 tile read 24B LDS / 16 FLOP (LDS-bound, 78us).  R8's
//      "SGPR weights" theory failed: compiler emitted per-lane VMEM loads ->
//      latency-bound at 18% VALUBusy (115us).  R9 keeps weights in LDS
//      (broadcast reads are free) but doubles FLOPs per LDS byte:
//      per 4-k-step/thread = 10 ds_read_b128 vs 64 FMA -> VALU-bound.
//      ins pitch 36 / tts pitch 68 (stride=4 mod 32 banks: conflict-free).

#define NB   256     // dst buckets
#define NPB  1024    // nodes per bucket (N = NB*NPB)
#define TILE 4096    // edges per partition tile
#define SRCMASK 0x3FFFFu

__device__ __forceinline__ float bf_lo(unsigned u) { return __uint_as_float(u << 16); }
__device__ __forceinline__ float bf_hi(unsigned u) { return __uint_as_float(u & 0xFFFF0000u); }
__device__ __forceinline__ unsigned bf_rne(float f) {   // fp32 -> bf16 bits (RNE)
    unsigned b = __float_as_uint(f);
    return (b + 0x7FFFu + ((b >> 16) & 1u)) >> 16;
}

// ---- P1: global bucket histogram -------------------------------------------
__global__ void hist_kernel(const int* __restrict__ dst, int* __restrict__ ghist,
                            int E, int shift) {
    __shared__ int h[NB];
    int tid = threadIdx.x;
    h[tid] = 0;
    __syncthreads();
    int base = blockIdx.x * TILE;
    int cnt = min(TILE, E - base);
    for (int i = tid; i < cnt; i += 256)
        atomicAdd(&h[dst[base + i] >> shift], 1);
    __syncthreads();
    int v = h[tid];
    if (v) atomicAdd(&ghist[tid], v);
}

// ---- P2: scan bucket counts -> bbase[NB+1], init gcursor -------------------
__global__ void bscan_kernel(const int* __restrict__ ghist, int* __restrict__ bbase,
                             int* __restrict__ gcursor) {
    __shared__ int sh[NB];
    int tid = threadIdx.x;
    int v = ghist[tid];
    sh[tid] = v;
    __syncthreads();
    for (int o = 1; o < NB; o <<= 1) {
        int t = (tid >= o) ? sh[tid - o] : 0;
        __syncthreads();
        sh[tid] += t;
        __syncthreads();
    }
    int incl = sh[tid];
    bbase[tid] = incl - v;
    gcursor[tid] = incl - v;
    if (tid == NB - 1) bbase[NB] = incl;
}

// ---- P3: partition edges into bucket-contiguous packed stream --------------
__global__ void __launch_bounds__(256)
partition_kernel(const int* __restrict__ src, const int* __restrict__ dst,
                 int* __restrict__ gcursor, unsigned int* __restrict__ bedge,
                 int E, int shift, int mask) {
    __shared__ int h[NB], st[NB], gp[NB];
    __shared__ unsigned short rk[TILE];
    __shared__ int sd[TILE];
    __shared__ int ss[TILE];
    int tid = threadIdx.x;
    h[tid] = 0;
    __syncthreads();
    int base = blockIdx.x * TILE;
    int cnt = min(TILE, E - base);
    for (int i = tid; i < cnt; i += 256)
        rk[i] = (unsigned short)atomicAdd(&h[dst[base + i] >> shift], 1);
    __syncthreads();
    int hv = h[tid];
    st[tid] = hv;
    __syncthreads();
    for (int o = 1; o < NB; o <<= 1) {
        int t = (tid >= o) ? st[tid - o] : 0;
        __syncthreads();
        st[tid] += t;
        __syncthreads();
    }
    st[tid] -= hv;
    gp[tid] = hv ? atomicAdd(&gcursor[tid], hv) : 0;
    __syncthreads();
    for (int i = tid; i < cnt; i += 256) {
        int d = dst[base + i];
        int b = d >> shift;
        int pos = st[b] + rk[i];
        sd[pos] = d;
        ss[pos] = src[base + i];
    }
    __syncthreads();
    for (int i = tid; i < cnt; i += 256) {
        int d = sd[i];
        int b = d >> shift;
        int g = gp[b] + (i - st[b]);
        bedge[g] = (unsigned int)ss[i] | ((unsigned int)(d & mask) << 18);
    }
}

// ---- P4: per-bucket CSR build + fused prescale -----------------------------
__global__ void __launch_bounds__(256)
build_kernel(const int* __restrict__ bbase, const unsigned int* __restrict__ bedge,
             const float* __restrict__ x,
             int* __restrict__ off, float* __restrict__ dinv, int* __restrict__ adj,
             float* __restrict__ y0) {
    __shared__ int deg1[NPB];
    __shared__ int cur[NPB];
    __shared__ int bs[256];
    int tid = threadIdx.x;
    int b = blockIdx.x;
    int s = bbase[b], e = bbase[b + 1];
    int base = tid * 4;
#pragma unroll
    for (int i = 0; i < 4; i++) deg1[base + i] = 0;
    __syncthreads();
    for (int i = s + tid; i < e; i += 256)
        atomicAdd(&deg1[bedge[i] >> 18], 1);
    __syncthreads();
    int d0 = deg1[base], d1 = deg1[base + 1], d2 = deg1[base + 2], d3 = deg1[base + 3];
    int th = d0 + d1 + d2 + d3;
    bs[tid] = th;
    __syncthreads();
    for (int o = 1; o < 256; o <<= 1) {
        int t = (tid >= o) ? bs[tid - o] : 0;
        __syncthreads();
        bs[tid] += t;
        __syncthreads();
    }
    int run = s + bs[tid] - th;
    int vb = b * NPB + base;
    off[vb]     = run; cur[base]     = run; dinv[vb]     = rsqrtf((float)(d0 + 1)); run += d0;
    off[vb + 1] = run; cur[base + 1] = run; dinv[vb + 1] = rsqrtf((float)(d1 + 1)); run += d1;
    off[vb + 2] = run; cur[base + 2] = run; dinv[vb + 2] = rsqrtf((float)(d2 + 1)); run += d2;
    off[vb + 3] = run; cur[base + 3] = run; dinv[vb + 3] = rsqrtf((float)(d3 + 1)); run += d3;
    if (b == NB - 1 && tid == 255) off[NB * NPB] = e;   // sentinel off[N] = E
    __syncthreads();
    for (int i = s + tid; i < e; i += 256) {
        unsigned int pk = bedge[i];
        int p = atomicAdd(&cur[pk >> 18], 1);
        adj[p] = (int)(pk & SRCMASK);
    }
    // fused prescale: y0[v] = dinv[v] * x[v]  (bucket rows, coalesced)
    for (int i = tid; i < NPB * 2; i += 256) {
        int v = i >> 1;
        float dv = rsqrtf((float)(deg1[v] + 1));
        float4 t = ((const float4*)x)[(size_t)b * NPB * 2 + i];
        t.x *= dv; t.y *= dv; t.z *= dv; t.w *= dv;
        ((float4*)y0)[(size_t)b * NPB * 2 + i] = t;
    }
}

// ---- Fused agg(8-dim) + transform 8->16 ------------------------------------
// gather: 2 lanes/node; epilogue: a1 = dinv*(sum+self) staged in LDS, then
// y1[v] = dinv[v]*relu(a1 @ W1 + b1).
__global__ void __launch_bounds__(256)
aggt1_kernel(const float* __restrict__ y0, const int* __restrict__ off,
             const int* __restrict__ adj, const float* __restrict__ dinv,
             const float* __restrict__ W1, const float* __restrict__ b1,
             float* __restrict__ y1) {
    __shared__ float Ws[8 * 16];
    __shared__ float bsh[16];
    __shared__ float sh[128][9];
    const int tid = threadIdx.x;
    if (tid < 128) Ws[tid] = W1[tid];
    if (tid < 16) bsh[tid] = b1[tid];
    const int vbase = blockIdx.x * 128;
    const int vl = tid >> 1, c = tid & 1;
    const int vg = vbase + vl;
    const float4* y4 = (const float4*)y0;
    int beg = off[vg];
    int end = off[vg + 1];
    float4 a0 = y4[(size_t)vg * 2 + c];   // self
    float4 a1, a2, a3;
    a1.x = a1.y = a1.z = a1.w = 0.f;
    a2.x = a2.y = a2.z = a2.w = 0.f;
    a3.x = a3.y = a3.z = a3.w = 0.f;
    int e = beg;
    for (; e + 4 <= end; e += 4) {
        int s0 = adj[e], s1 = adj[e + 1], s2 = adj[e + 2], s3 = adj[e + 3];
        float4 x0 = y4[(size_t)s0 * 2 + c];
        float4 x1 = y4[(size_t)s1 * 2 + c];
        float4 x2 = y4[(size_t)s2 * 2 + c];
        float4 x3 = y4[(size_t)s3 * 2 + c];
        a0.x += x0.x; a0.y += x0.y; a0.z += x0.z; a0.w += x0.w;
        a1.x += x1.x; a1.y += x1.y; a1.z += x1.z; a1.w += x1.w;
        a2.x += x2.x; a2.y += x2.y; a2.z += x2.z; a2.w += x2.w;
        a3.x += x3.x; a3.y += x3.y; a3.z += x3.z; a3.w += x3.w;
    }
    for (; e < end; e++) {
        float4 xs = y4[(size_t)adj[e] * 2 + c];
        a1.x += xs.x; a1.y += xs.y; a1.z += xs.z; a1.w += xs.w;
    }
    float dv = dinv[vg];
    sh[vl][c * 4 + 0] = ((a0.x + a1.x) + (a2.x + a3.x)) * dv;
    sh[vl][c * 4 + 1] = ((a0.y + a1.y) + (a2.y + a3.y)) * dv;
    sh[vl][c * 4 + 2] = ((a0.z + a1.z) + (a2.z + a3.z)) * dv;
    sh[vl][c * 4 + 3] = ((a0.w + a1.w) + (a2.w + a3.w)) * dv;
    __syncthreads();
    // transform: thread -> (node nl, half hf), 8 outputs
    const int nl = tid & 127, hf = tid >> 7, j0 = hf * 8;
    float in0 = sh[nl][0], in1 = sh[nl][1], in2 = sh[nl][2], in3 = sh[nl][3];
    float in4 = sh[nl][4], in5 = sh[nl][5], in6 = sh[nl][6], in7 = sh[nl][7];
    float dn = dinv[vbase + nl];
    float o[8];
#pragma unroll
    for (int jj = 0; jj < 8; jj++) {
        int j = j0 + jj;
        float acc = bsh[j];
        acc += in0 * Ws[0 * 16 + j]; acc += in1 * Ws[1 * 16 + j];
        acc += in2 * Ws[2 * 16 + j]; acc += in3 * Ws[3 * 16 + j];
        acc += in4 * Ws[4 * 16 + j]; acc += in5 * Ws[5 * 16 + j];
        acc += in6 * Ws[6 * 16 + j]; acc += in7 * Ws[7 * 16 + j];
        o[jj] = dn * fmaxf(acc, 0.f);
    }
    float4* out4 = (float4*)(y1 + (size_t)(vbase + nl) * 16 + j0);
    float4 t0; t0.x = o[0]; t0.y = o[1]; t0.z = o[2]; t0.w = o[3];
    float4 t1; t1.x = o[4]; t1.y = o[5]; t1.z = o[6]; t1.w = o[7];
    out4[0] = t0; out4[1] = t1;
}

// ---- Fused agg(16-dim) + transform 16->32, bf16 output ---------------------
__global__ void __launch_bounds__(256)
aggt2_kernel(const float* __restrict__ y1, const int* __restrict__ off,
             const int* __restrict__ adj, const float* __restrict__ dinv,
             const float* __restrict__ W2, const float* __restrict__ b2,
             unsigned int* __restrict__ y2b) {
    __shared__ float Ws[16 * 32];
    __shared__ float bsh[32];
    __shared__ float sh[64][17];
    const int tid = threadIdx.x;
    for (int i = tid; i < 16 * 32; i += 256) Ws[i] = W2[i];
    if (tid < 32) bsh[tid] = b2[tid];
    const int vbase = blockIdx.x * 64;
    const int vl = tid >> 2, c = tid & 3;
    const int vg = vbase + vl;
    const float4* y4 = (const float4*)y1;
    int beg = off[vg];
    int end = off[vg + 1];
    float4 a0 = y4[(size_t)vg * 4 + c];   // self
    float4 a1, a2, a3;
    a1.x = a1.y = a1.z = a1.w = 0.f;
    a2.x = a2.y = a2.z = a2.w = 0.f;
    a3.x = a3.y = a3.z = a3.w = 0.f;
    int e = beg;
    for (; e + 4 <= end; e += 4) {
        int s0 = adj[e], s1 = adj[e + 1], s2 = adj[e + 2], s3 = adj[e + 3];
        float4 x0 = y4[(size_t)s0 * 4 + c];
        float4 x1 = y4[(size_t)s1 * 4 + c];
        float4 x2 = y4[(size_t)s2 * 4 + c];
        float4 x3 = y4[(size_t)s3 * 4 + c];
        a0.x += x0.x; a0.y += x0.y; a0.z += x0.z; a0.w += x0.w;
        a1.x += x1.x; a1.y += x1.y; a1.z += x1.z; a1.w += x1.w;
        a2.x += x2.x; a2.y += x2.y; a2.z += x2.z; a2.w += x2.w;
        a3.x += x3.x; a3.y += x3.y; a3.z += x3.z; a3.w += x3.w;
    }
    for (; e < end; e++) {
        float4 xs = y4[(size_t)adj[e] * 4 + c];
        a1.x += xs.x; a1.y += xs.y; a1.z += xs.z; a1.w += xs.w;
    }
    float dv = dinv[vg];
    sh[vl][c * 4 + 0] = ((a0.x + a1.x) + (a2.x + a3.x)) * dv;
    sh[vl][c * 4 + 1] = ((a0.y + a1.y) + (a2.y + a3.y)) * dv;
    sh[vl][c * 4 + 2] = ((a0.z + a1.z) + (a2.z + a3.z)) * dv;
    sh[vl][c * 4 + 3] = ((a0.w + a1.w) + (a2.w + a3.w)) * dv;
    __syncthreads();
    // transform: thread -> (node nl, quarter q), 8 outputs, pack bf16
    const int nl = tid & 63, q = tid >> 6, j0 = q * 8;
    float in[16];
#pragma unroll
    for (int k = 0; k < 16; k++) in[k] = sh[nl][k];
    float dn = dinv[vbase + nl];
    unsigned r[8];
#pragma unroll
    for (int jj = 0; jj < 8; jj++) {
        int j = j0 + jj;
        float acc = bsh[j];
#pragma unroll
        for (int k = 0; k < 16; k++) acc += in[k] * Ws[k * 32 + j];
        r[jj] = bf_rne(dn * fmaxf(acc, 0.f));
    }
    uint4 pk;
    pk.x = r[0] | (r[1] << 16); pk.y = r[2] | (r[3] << 16);
    pk.z = r[4] | (r[5] << 16); pk.w = r[6] | (r[7] << 16);
    ((uint4*)y2b)[(size_t)(vbase + nl) * 4 + q] = pk;
}

// ---- agg(32-dim, bf16 rows) -> fp32 a3 -------------------------------------
// 4 lanes/node, each lane one uint4 (8 bf16) chunk; 2-way unrolled.
__global__ void __launch_bounds__(256)
agg_bf16_kernel(const unsigned int* __restrict__ y2b, const int* __restrict__ off,
                const int* __restrict__ adj, const float* __restrict__ dinv,
                float* __restrict__ a3out, int n) {
    int t = blockIdx.x * 256 + threadIdx.x;
    int v = t >> 2, c = t & 3;
    if (v >= n) return;
    const uint4* yb = (const uint4*)y2b;
    uint4 us = yb[(size_t)v * 4 + c];   // self
    float p0 = bf_lo(us.x), p1 = bf_hi(us.x), p2 = bf_lo(us.y), p3 = bf_hi(us.y);
    float p4 = bf_lo(us.z), p5 = bf_hi(us.z), p6 = bf_lo(us.w), p7 = bf_hi(us.w);
    float q0 = 0, q1 = 0, q2 = 0, q3 = 0, q4 = 0, q5 = 0, q6 = 0, q7 = 0;
    int beg = off[v], end = off[v + 1];
    int e = beg;
    for (; e + 2 <= end; e += 2) {
        int s0 = adj[e], s1 = adj[e + 1];
        uint4 u0 = yb[(size_t)s0 * 4 + c];
        uint4 u1 = yb[(size_t)s1 * 4 + c];
        p0 += bf_lo(u0.x); p1 += bf_hi(u0.x); p2 += bf_lo(u0.y); p3 += bf_hi(u0.y);
        p4 += bf_lo(u0.z); p5 += bf_hi(u0.z); p6 += bf_lo(u0.w); p7 += bf_hi(u0.w);
        q0 += bf_lo(u1.x); q1 += bf_hi(u1.x); q2 += bf_lo(u1.y); q3 += bf_hi(u1.y);
        q4 += bf_lo(u1.z); q5 += bf_hi(u1.z); q6 += bf_lo(u1.w); q7 += bf_hi(u1.w);
    }
    if (e < end) {
        uint4 u0 = yb[(size_t)adj[e] * 4 + c];
        p0 += bf_lo(u0.x); p1 += bf_hi(u0.x); p2 += bf_lo(u0.y); p3 += bf_hi(u0.y);
        p4 += bf_lo(u0.z); p5 += bf_hi(u0.z); p6 += bf_lo(u0.w); p7 += bf_hi(u0.w);
    }
    float dv = dinv[v];
    float4 o0, o1;
    o0.x = (p0 + q0) * dv; o0.y = (p1 + q1) * dv; o0.z = (p2 + q2) * dv; o0.w = (p3 + q3) * dv;
    o1.x = (p4 + q4) * dv; o1.y = (p5 + q5) * dv; o1.z = (p6 + q6) * dv; o1.w = (p7 + q7) * dv;
    float4* out4 = (float4*)a3out;
    out4[(size_t)v * 8 + c * 2]     = o0;
    out4[(size_t)v * 8 + c * 2 + 1] = o1;
}

// ---- Fused layer-3 transform + FC (block-cooperative, 2x8 reg tile) --------
// R9: 256 threads, 64 nodes/block.  Thread (tx=tid&7, ty=tid>>3) computes
// nodes {ty, ty+32} x cols [8tx, 8tx+8).  Per 4-k-step: 2 b128 x-reads +
// 8 b128 W-reads feed 64 FMA instrs -> VALU-bound (R7's 2x4 tile was
// LDS-bound: 3 LDS instr per 8 FMA).  ins pitch 36 / tts pitch 68: row
// stride = 4 mod 32 banks -> 8 rows x float4 cover all 32 banks, 8-way
// broadcast, conflict-free.  W reads: 8 distinct 16B addrs, 2 per bank
// quad (2-way = free), 8-way broadcast.  LDS 50.5KB -> 3 blocks/CU.
#define T3_NODES 64
#define INS_P 36
#define TTS_P 68

#define FMA8(acc, wa, wb, xv) \
    acc[0] = fmaf(xv, wa.x, acc[0]); acc[1] = fmaf(xv, wa.y, acc[1]); \
    acc[2] = fmaf(xv, wa.z, acc[2]); acc[3] = fmaf(xv, wa.w, acc[3]); \
    acc[4] = fmaf(xv, wb.x, acc[4]); acc[5] = fmaf(xv, wb.y, acc[5]); \
    acc[6] = fmaf(xv, wb.z, acc[6]); acc[7] = fmaf(xv, wb.w, acc[7]);

__global__ void __launch_bounds__(256)
t3fc_kernel(const float* __restrict__ in,
            const float* __restrict__ W3, const float* __restrict__ b3,
            const float* __restrict__ Wf, const float* __restrict__ bf,
            float* __restrict__ out, int n) {
    __shared__ float W3s[32 * 64];
    __shared__ float Wfs[64 * 64];
    __shared__ float b3s[64], bfs[64];
    __shared__ float ins[T3_NODES][INS_P];
    __shared__ float tts[T3_NODES][TTS_P];
    const int tid = threadIdx.x;
    for (int i = tid; i < 32 * 64; i += 256) W3s[i] = W3[i];
    for (int i = tid; i < 64 * 64; i += 256) Wfs[i] = Wf[i];
    if (tid < 64) { b3s[tid] = b3[tid]; bfs[tid] = bf[tid]; }
    const int vbase = blockIdx.x * T3_NODES;
    {
        const float4* g = (const float4*)(in + (size_t)vbase * 32);
        float4 t = g[tid];
        int v = tid >> 3, c = (tid & 7) * 4;
        *(float4*)&ins[v][c] = t;
        t = g[tid + 256];
        v = (tid + 256) >> 3; c = (tid & 7) * 4;
        *(float4*)&ins[v][c] = t;
    }
    __syncthreads();
    const int tx = tid & 7;
    const int ty = tid >> 3;          // 0..31
    const int j0 = tx * 8;
    // ---- GEMM1: [64x32] @ [32x64], k fully unrolled by 4 ----
    float a0[8], a1[8];
#pragma unroll
    for (int jj = 0; jj < 8; jj++) { a0[jj] = b3s[j0 + jj]; a1[jj] = a0[jj]; }
#pragma unroll
    for (int k0 = 0; k0 < 32; k0 += 4) {
        float4 x0 = *(const float4*)&ins[ty][k0];
        float4 x1 = *(const float4*)&ins[ty + 32][k0];
        const float* wp = &W3s[k0 * 64 + j0];
        float4 wa, wb;
        wa = *(const float4*)(wp);       wb = *(const float4*)(wp + 4);
        FMA8(a0, wa, wb, x0.x); FMA8(a1, wa, wb, x1.x);
        wa = *(const float4*)(wp + 64);  wb = *(const float4*)(wp + 68);
        FMA8(a0, wa, wb, x0.y); FMA8(a1, wa, wb, x1.y);
        wa = *(const float4*)(wp + 128); wb = *(const float4*)(wp + 132);
        FMA8(a0, wa, wb, x0.z); FMA8(a1, wa, wb, x1.z);
        wa = *(const float4*)(wp + 192); wb = *(const float4*)(wp + 196);
        FMA8(a0, wa, wb, x0.w); FMA8(a1, wa, wb, x1.w);
    }
    // relu -> tts
    {
        float4 r;
        r.x = fmaxf(a0[0], 0.f); r.y = fmaxf(a0[1], 0.f);
        r.z = fmaxf(a0[2], 0.f); r.w = fmaxf(a0[3], 0.f);
        *(float4*)&tts[ty][j0] = r;
        r.x = fmaxf(a0[4], 0.f); r.y = fmaxf(a0[5], 0.f);
        r.z = fmaxf(a0[6], 0.f); r.w = fmaxf(a0[7], 0.f);
        *(float4*)&tts[ty][j0 + 4] = r;
        r.x = fmaxf(a1[0], 0.f); r.y = fmaxf(a1[1], 0.f);
        r.z = fmaxf(a1[2], 0.f); r.w = fmaxf(a1[3], 0.f);
        *(float4*)&tts[ty + 32][j0] = r;
        r.x = fmaxf(a1[4], 0.f); r.y = fmaxf(a1[5], 0.f);
        r.z = fmaxf(a1[6], 0.f); r.w = fmaxf(a1[7], 0.f);
        *(float4*)&tts[ty + 32][j0 + 4] = r;
    }
    __syncthreads();
    // ---- GEMM2: [64x64] @ [64x64], k fully unrolled by 4 ----
    float c0[8], c1[8];
#pragma unroll
    for (int jj = 0; jj < 8; jj++) { c0[jj] = bfs[j0 + jj]; c1[jj] = c0[jj]; }
#pragma unroll
    for (int k0 = 0; k0 < 64; k0 += 4) {
        float4 x0 = *(const float4*)&tts[ty][k0];
        float4 x1 = *(const float4*)&tts[ty + 32][k0];
        const float* wp = &Wfs[k0 * 64 + j0];
        float4 wa, wb;
        wa = *(const float4*)(wp);       wb = *(const float4*)(wp + 4);
        FMA8(c0, wa, wb, x0.x); FMA8(c1, wa, wb, x1.x);
        wa = *(const float4*)(wp + 64);  wb = *(const float4*)(wp + 68);
        FMA8(c0, wa, wb, x0.y); FMA8(c1, wa, wb, x1.y);
        wa = *(const float4*)(wp + 128); wb = *(const float4*)(wp + 132);
        FMA8(c0, wa, wb, x0.z); FMA8(c1, wa, wb, x1.z);
        wa = *(const float4*)(wp + 192); wb = *(const float4*)(wp + 196);
        FMA8(c0, wa, wb, x0.w); FMA8(c1, wa, wb, x1.w);
    }
    // ---- epilogue: coalesced float4 stores ----
    {
        float4 o;
        float* p0 = out + ((size_t)(vbase + ty)) * 64 + j0;
        o.x = c0[0]; o.y = c0[1]; o.z = c0[2]; o.w = c0[3];
        *(float4*)p0 = o;
        o.x = c0[4]; o.y = c0[5]; o.z = c0[6]; o.w = c0[7];
        *(float4*)(p0 + 4) = o;
        float* p1 = out + ((size_t)(vbase + ty + 32)) * 64 + j0;
        o.x = c1[0]; o.y = c1[1]; o.z = c1[2]; o.w = c1[3];
        *(float4*)p1 = o;
        o.x = c1[4]; o.y = c1[5]; o.z = c1[6]; o.w = c1[7];
        *(float4*)(p1 + 4) = o;
    }
}

extern "C" void kernel_launch(void* const* d_in, const int* in_sizes, int n_in,
                              void* d_out, int out_size, void* d_ws, size_t ws_size,
                              hipStream_t stream) {
    const float* x  = (const float*)d_in[0];
    const float* W1 = (const float*)d_in[1];
    const float* b1 = (const float*)d_in[2];
    const float* W2 = (const float*)d_in[3];
    const float* b2 = (const float*)d_in[4];
    const float* W3 = (const float*)d_in[5];
    const float* b3 = (const float*)d_in[6];
    const float* Wf = (const float*)d_in[7];
    const float* bf = (const float*)d_in[8];
    const int*   ei = (const int*)d_in[9];

    const int N = in_sizes[0] / 8;   // 262144
    const int E = in_sizes[9] / 2;   // 2097152
    const int* srcv = ei;
    const int* dstv = ei + E;
    const int shift = 10;            // log2(NPB)

    // Workspace layout (16B-aligned chunks)
    char* p = (char*)d_ws;
    auto take = [&p](size_t bytes) { char* q = p; p += (bytes + 63) & ~size_t(63); return q; };
    int*   off   = (int*)take((size_t)(N + 16) * 4);
    float* dinv  = (float*)take((size_t)N * 4);
    int*   adj   = (int*)take((size_t)E * 4);
    int*   ghist = (int*)take(NB * 4);
    int*   bbase = (int*)take((NB + 1) * 4);
    int*   gcur  = (int*)take(NB * 4);
    float* bufA  = (float*)take((size_t)N * 32 * 4);   // y0 [0,8MB) then a3 (33MB)
    float* y1    = (float*)take((size_t)N * 16 * 4);   // 16MB
    char*  regX  = take((size_t)N * 32 * 2);           // 16MB: bedge (8MB) then y2b
    unsigned int* bedge = (unsigned int*)regX;
    unsigned int* y2b   = (unsigned int*)regX;
    float* y0 = bufA;

    hipMemsetAsync(ghist, 0, NB * 4, stream);

    int nt = (E + TILE - 1) / TILE;  // 512 tiles
    hist_kernel<<<nt, 256, 0, stream>>>(dstv, ghist, E, shift);
    bscan_kernel<<<1, NB, 0, stream>>>(ghist, bbase, gcur);
    partition_kernel<<<nt, 256, 0, stream>>>(srcv, dstv, gcur, bedge, E, shift, NPB - 1);
    build_kernel<<<NB, 256, 0, stream>>>(bbase, bedge, x, off, dinv, adj, y0);

    // L1: agg(y0) + transform 8->16 -> y1
    aggt1_kernel<<<N / 128, 256, 0, stream>>>(y0, off, adj, dinv, W1, b1, y1);
    // L2: agg(y1) + transform 16->32 -> y2b (bf16; overwrites dead bedge)
    aggt2_kernel<<<N / 64, 256, 0, stream>>>(y1, off, adj, dinv, W2, b2, y2b);
    // L3: agg(y2b) -> a3 (bufA; y0 dead), then fused transform+FC -> out
    agg_bf16_kernel<<<(N * 4) / 256, 256, 0, stream>>>(y2b, off, adj, dinv, bufA, N);
    t3fc_kernel<<<N / T3_NODES, 256, 0, stream>>>(bufA, W3, b3, Wf, bf, (float*)d_out, N);
}

// Round 4
// 306.502 us; speedup vs baseline: 1.2452x; 1.1032x over previous
//
#include <hip/hip_runtime.h>
#include <hip/hip_bf16.h>

// GCN x3 + FC on a fixed random graph.
//   1. Bucket-partition CSR build: hist -> scan -> packed partition
//      (src|dl<<18) -> per-bucket build (LDS atomics, coalesced I/O) with
//      fused prescale y0 = dinv*x.
//   2. Pull aggregation over pre-scaled features y = dinv*h:
//      out[v] = dinv[v]*(sum y[s] + y[v]).  Transform fused into agg epilogue
//      via per-block LDS staging (aggt1: 8->16, aggt2: 16->32).
//   3. y2 stored bf16 (64B rows): halves agg3's random-gather sectors.
//      a3 stored fp16 (R10): halves agg3 writes + t3fc fetch.
//   4. t3fc (R10/R11 resubmit -- R10 bench was an infra failure, audit clean):
//      MFMA.  fp32 VALU path is structurally LDS-return-bound (R9: 10 b128
//      per 4-k-step vs 64 FMA -> LDS pipe needs 2.5-3.7x the FMA cycles at
//      ANY register-tile shape; measured 64us @48% VALUBusy).
//      mfma_f32_16x16x32_f16 amortizes 1KB operand traffic per 16K FLOP.
//      Weights pre-converted to B-frag-ordered fp16 (in bscan, once) ->
//      t3fc reads B-frags straight from global (12KB, L1-hot; no LDS
//      staging, no barrier).  Per wave: 16 nodes; A1-frag from global;
//      4 MFMA -> relu -> fp16 -> per-wave frag-ordered LDS (2KB) ->
//      8 MFMA -> store.  Frag maps (m89-verified): A row=l&15,
//      k=(l>>4)*8+j; B col=l&15 same k; D col=l&15, row=(l>>4)*4+reg.

#define NB   256     // dst buckets
#define NPB  1024    // nodes per bucket (N = NB*NPB)
#define TILE 4096    // edges per partition tile
#define SRCMASK 0x3FFFFu

typedef _Float16 half8 __attribute__((ext_vector_type(8)));
typedef float float4v __attribute__((ext_vector_type(4)));

__device__ __forceinline__ float bf_lo(unsigned u) { return __uint_as_float(u << 16); }
__device__ __forceinline__ float bf_hi(unsigned u) { return __uint_as_float(u & 0xFFFF0000u); }
__device__ __forceinline__ unsigned bf_rne(float f) {   // fp32 -> bf16 bits (RNE)
    unsigned b = __float_as_uint(f);
    return (b + 0x7FFFu + ((b >> 16) & 1u)) >> 16;
}
__device__ __forceinline__ unsigned pkh(float a, float b) {  // 2x fp32 -> packed fp16 (RNE)
    unsigned short ua = __builtin_bit_cast(unsigned short, (_Float16)a);
    unsigned short ub = __builtin_bit_cast(unsigned short, (_Float16)b);
    return (unsigned)ua | ((unsigned)ub << 16);
}

// ---- P1: global bucket histogram -------------------------------------------
__global__ void hist_kernel(const int* __restrict__ dst, int* __restrict__ ghist,
                            int E, int shift) {
    __shared__ int h[NB];
    int tid = threadIdx.x;
    h[tid] = 0;
    __syncthreads();
    int base = blockIdx.x * TILE;
    int cnt = min(TILE, E - base);
    for (int i = tid; i < cnt; i += 256)
        atomicAdd(&h[dst[base + i] >> shift], 1);
    __syncthreads();
    int v = h[tid];
    if (v) atomicAdd(&ghist[tid], v);
}

// ---- P2: scan bucket counts + fused weight->fp16 frag conversion -----------
// Frag order for B of mfma_f32_16x16x32_f16: dest[( (k>>5)*4 + (j>>4) )*512
//  + (j&15)*32 + ((k>>3)&3)*8 + (k&7)]  (j = col, k = row of W[k][j]).
__global__ void bscan_kernel(const int* __restrict__ ghist, int* __restrict__ bbase,
                             int* __restrict__ gcursor,
                             const float* __restrict__ W3, const float* __restrict__ Wf,
                             _Float16* __restrict__ w3f, _Float16* __restrict__ wff) {
    __shared__ int sh[NB];
    int tid = threadIdx.x;
    int v = ghist[tid];
    sh[tid] = v;
    __syncthreads();
    for (int o = 1; o < NB; o <<= 1) {
        int t = (tid >= o) ? sh[tid - o] : 0;
        __syncthreads();
        sh[tid] += t;
        __syncthreads();
    }
    int incl = sh[tid];
    bbase[tid] = incl - v;
    gcursor[tid] = incl - v;
    if (tid == NB - 1) bbase[NB] = incl;
    // W3: [32][64]
    for (int i = tid; i < 32 * 64; i += NB) {
        int k = i >> 6, j = i & 63;
        w3f[(j >> 4) * 512 + (j & 15) * 32 + (k >> 3) * 8 + (k & 7)] = (_Float16)W3[i];
    }
    // Wf: [64][64]
    for (int i = tid; i < 64 * 64; i += NB) {
        int k = i >> 6, j = i & 63;
        wff[((k >> 5) * 4 + (j >> 4)) * 512 + (j & 15) * 32 + ((k >> 3) & 3) * 8 + (k & 7)]
            = (_Float16)Wf[i];
    }
}

// ---- P3: partition edges into bucket-contiguous packed stream --------------
__global__ void __launch_bounds__(256)
partition_kernel(const int* __restrict__ src, const int* __restrict__ dst,
                 int* __restrict__ gcursor, unsigned int* __restrict__ bedge,
                 int E, int shift, int mask) {
    __shared__ int h[NB], st[NB], gp[NB];
    __shared__ unsigned short rk[TILE];
    __shared__ int sd[TILE];
    __shared__ int ss[TILE];
    int tid = threadIdx.x;
    h[tid] = 0;
    __syncthreads();
    int base = blockIdx.x * TILE;
    int cnt = min(TILE, E - base);
    for (int i = tid; i < cnt; i += 256)
        rk[i] = (unsigned short)atomicAdd(&h[dst[base + i] >> shift], 1);
    __syncthreads();
    int hv = h[tid];
    st[tid] = hv;
    __syncthreads();
    for (int o = 1; o < NB; o <<= 1) {
        int t = (tid >= o) ? st[tid - o] : 0;
        __syncthreads();
        st[tid] += t;
        __syncthreads();
    }
    st[tid] -= hv;
    gp[tid] = hv ? atomicAdd(&gcursor[tid], hv) : 0;
    __syncthreads();
    for (int i = tid; i < cnt; i += 256) {
        int d = dst[base + i];
        int b = d >> shift;
        int pos = st[b] + rk[i];
        sd[pos] = d;
        ss[pos] = src[base + i];
    }
    __syncthreads();
    for (int i = tid; i < cnt; i += 256) {
        int d = sd[i];
        int b = d >> shift;
        int g = gp[b] + (i - st[b]);
        bedge[g] = (unsigned int)ss[i] | ((unsigned int)(d & mask) << 18);
    }
}

// ---- P4: per-bucket CSR build + fused prescale -----------------------------
__global__ void __launch_bounds__(256)
build_kernel(const int* __restrict__ bbase, const unsigned int* __restrict__ bedge,
             const float* __restrict__ x,
             int* __restrict__ off, float* __restrict__ dinv, int* __restrict__ adj,
             float* __restrict__ y0) {
    __shared__ int deg1[NPB];
    __shared__ int cur[NPB];
    __shared__ int bs[256];
    int tid = threadIdx.x;
    int b = blockIdx.x;
    int s = bbase[b], e = bbase[b + 1];
    int base = tid * 4;
#pragma unroll
    for (int i = 0; i < 4; i++) deg1[base + i] = 0;
    __syncthreads();
    for (int i = s + tid; i < e; i += 256)
        atomicAdd(&deg1[bedge[i] >> 18], 1);
    __syncthreads();
    int d0 = deg1[base], d1 = deg1[base + 1], d2 = deg1[base + 2], d3 = deg1[base + 3];
    int th = d0 + d1 + d2 + d3;
    bs[tid] = th;
    __syncthreads();
    for (int o = 1; o < 256; o <<= 1) {
        int t = (tid >= o) ? bs[tid - o] : 0;
        __syncthreads();
        bs[tid] += t;
        __syncthreads();
    }
    int run = s + bs[tid] - th;
    int vb = b * NPB + base;
    off[vb]     = run; cur[base]     = run; dinv[vb]     = rsqrtf((float)(d0 + 1)); run += d0;
    off[vb + 1] = run; cur[base + 1] = run; dinv[vb + 1] = rsqrtf((float)(d1 + 1)); run += d1;
    off[vb + 2] = run; cur[base + 2] = run; dinv[vb + 2] = rsqrtf((float)(d2 + 1)); run += d2;
    off[vb + 3] = run; cur[base + 3] = run; dinv[vb + 3] = rsqrtf((float)(d3 + 1)); run += d3;
    if (b == NB - 1 && tid == 255) off[NB * NPB] = e;   // sentinel off[N] = E
    __syncthreads();
    for (int i = s + tid; i < e; i += 256) {
        unsigned int pk = bedge[i];
        int p = atomicAdd(&cur[pk >> 18], 1);
        adj[p] = (int)(pk & SRCMASK);
    }
    // fused prescale: y0[v] = dinv[v] * x[v]  (bucket rows, coalesced)
    for (int i = tid; i < NPB * 2; i += 256) {
        int v = i >> 1;
        float dv = rsqrtf((float)(deg1[v] + 1));
        float4 t = ((const float4*)x)[(size_t)b * NPB * 2 + i];
        t.x *= dv; t.y *= dv; t.z *= dv; t.w *= dv;
        ((float4*)y0)[(size_t)b * NPB * 2 + i] = t;
    }
}

// ---- Fused agg(8-dim) + transform 8->16 ------------------------------------
__global__ void __launch_bounds__(256)
aggt1_kernel(const float* __restrict__ y0, const int* __restrict__ off,
             const int* __restrict__ adj, const float* __restrict__ dinv,
             const float* __restrict__ W1, const float* __restrict__ b1,
             float* __restrict__ y1) {
    __shared__ float Ws[8 * 16];
    __shared__ float bsh[16];
    __shared__ float sh[128][9];
    const int tid = threadIdx.x;
    if (tid < 128) Ws[tid] = W1[tid];
    if (tid < 16) bsh[tid] = b1[tid];
    const int vbase = blockIdx.x * 128;
    const int vl = tid >> 1, c = tid & 1;
    const int vg = vbase + vl;
    const float4* y4 = (const float4*)y0;
    int beg = off[vg];
    int end = off[vg + 1];
    float4 a0 = y4[(size_t)vg * 2 + c];   // self
    float4 a1, a2, a3;
    a1.x = a1.y = a1.z = a1.w = 0.f;
    a2.x = a2.y = a2.z = a2.w = 0.f;
    a3.x = a3.y = a3.z = a3.w = 0.f;
    int e = beg;
    for (; e + 4 <= end; e += 4) {
        int s0 = adj[e], s1 = adj[e + 1], s2 = adj[e + 2], s3 = adj[e + 3];
        float4 x0 = y4[(size_t)s0 * 2 + c];
        float4 x1 = y4[(size_t)s1 * 2 + c];
        float4 x2 = y4[(size_t)s2 * 2 + c];
        float4 x3 = y4[(size_t)s3 * 2 + c];
        a0.x += x0.x; a0.y += x0.y; a0.z += x0.z; a0.w += x0.w;
        a1.x += x1.x; a1.y += x1.y; a1.z += x1.z; a1.w += x1.w;
        a2.x += x2.x; a2.y += x2.y; a2.z += x2.z; a2.w += x2.w;
        a3.x += x3.x; a3.y += x3.y; a3.z += x3.z; a3.w += x3.w;
    }
    for (; e < end; e++) {
        float4 xs = y4[(size_t)adj[e] * 2 + c];
        a1.x += xs.x; a1.y += xs.y; a1.z += xs.z; a1.w += xs.w;
    }
    float dv = dinv[vg];
    sh[vl][c * 4 + 0] = ((a0.x + a1.x) + (a2.x + a3.x)) * dv;
    sh[vl][c * 4 + 1] = ((a0.y + a1.y) + (a2.y + a3.y)) * dv;
    sh[vl][c * 4 + 2] = ((a0.z + a1.z) + (a2.z + a3.z)) * dv;
    sh[vl][c * 4 + 3] = ((a0.w + a1.w) + (a2.w + a3.w)) * dv;
    __syncthreads();
    // transform: thread -> (node nl, half hf), 8 outputs
    const int nl = tid & 127, hf = tid >> 7, j0 = hf * 8;
    float in0 = sh[nl][0], in1 = sh[nl][1], in2 = sh[nl][2], in3 = sh[nl][3];
    float in4 = sh[nl][4], in5 = sh[nl][5], in6 = sh[nl][6], in7 = sh[nl][7];
    float dn = dinv[vbase + nl];
    float o[8];
#pragma unroll
    for (int jj = 0; jj < 8; jj++) {
        int j = j0 + jj;
        float acc = bsh[j];
        acc += in0 * Ws[0 * 16 + j]; acc += in1 * Ws[1 * 16 + j];
        acc += in2 * Ws[2 * 16 + j]; acc += in3 * Ws[3 * 16 + j];
        acc += in4 * Ws[4 * 16 + j]; acc += in5 * Ws[5 * 16 + j];
        acc += in6 * Ws[6 * 16 + j]; acc += in7 * Ws[7 * 16 + j];
        o[jj] = dn * fmaxf(acc, 0.f);
    }
    float4* out4 = (float4*)(y1 + (size_t)(vbase + nl) * 16 + j0);
    float4 t0; t0.x = o[0]; t0.y = o[1]; t0.z = o[2]; t0.w = o[3];
    float4 t1; t1.x = o[4]; t1.y = o[5]; t1.z = o[6]; t1.w = o[7];
    out4[0] = t0; out4[1] = t1;
}

// ---- Fused agg(16-dim) + transform 16->32, bf16 output ---------------------
__global__ void __launch_bounds__(256)
aggt2_kernel(const float* __restrict__ y1, const int* __restrict__ off,
             const int* __restrict__ adj, const float* __restrict__ dinv,
             const float* __restrict__ W2, const float* __restrict__ b2,
             unsigned int* __restrict__ y2b) {
    __shared__ float Ws[16 * 32];
    __shared__ float bsh[32];
    __shared__ float sh[64][17];
    const int tid = threadIdx.x;
    for (int i = tid; i < 16 * 32; i += 256) Ws[i] = W2[i];
    if (tid < 32) bsh[tid] = b2[tid];
    const int vbase = blockIdx.x * 64;
    const int vl = tid >> 2, c = tid & 3;
    const int vg = vbase + vl;
    const float4* y4 = (const float4*)y1;
    int beg = off[vg];
    int end = off[vg + 1];
    float4 a0 = y4[(size_t)vg * 4 + c];   // self
    float4 a1, a2, a3;
    a1.x = a1.y = a1.z = a1.w = 0.f;
    a2.x = a2.y = a2.z = a2.w = 0.f;
    a3.x = a3.y = a3.z = a3.w = 0.f;
    int e = beg;
    for (; e + 4 <= end; e += 4) {
        int s0 = adj[e], s1 = adj[e + 1], s2 = adj[e + 2], s3 = adj[e + 3];
        float4 x0 = y4[(size_t)s0 * 4 + c];
        float4 x1 = y4[(size_t)s1 * 4 + c];
        float4 x2 = y4[(size_t)s2 * 4 + c];
        float4 x3 = y4[(size_t)s3 * 4 + c];
        a0.x += x0.x; a0.y += x0.y; a0.z += x0.z; a0.w += x0.w;
        a1.x += x1.x; a1.y += x1.y; a1.z += x1.z; a1.w += x1.w;
        a2.x += x2.x; a2.y += x2.y; a2.z += x2.z; a2.w += x2.w;
        a3.x += x3.x; a3.y += x3.y; a3.z += x3.z; a3.w += x3.w;
    }
    for (; e < end; e++) {
        float4 xs = y4[(size_t)adj[e] * 4 + c];
        a1.x += xs.x; a1.y += xs.y; a1.z += xs.z; a1.w += xs.w;
    }
    float dv = dinv[vg];
    sh[vl][c * 4 + 0] = ((a0.x + a1.x) + (a2.x + a3.x)) * dv;
    sh[vl][c * 4 + 1] = ((a0.y + a1.y) + (a2.y + a3.y)) * dv;
    sh[vl][c * 4 + 2] = ((a0.z + a1.z) + (a2.z + a3.z)) * dv;
    sh[vl][c * 4 + 3] = ((a0.w + a1.w) + (a2.w + a3.w)) * dv;
    __syncthreads();
    // transform: thread -> (node nl, quarter q), 8 outputs, pack bf16
    const int nl = tid & 63, q = tid >> 6, j0 = q * 8;
    float in[16];
#pragma unroll
    for (int k = 0; k < 16; k++) in[k] = sh[nl][k];
    float dn = dinv[vbase + nl];
    unsigned r[8];
#pragma unroll
    for (int jj = 0; jj < 8; jj++) {
        int j = j0 + jj;
        float acc = bsh[j];
#pragma unroll
        for (int k = 0; k < 16; k++) acc += in[k] * Ws[k * 32 + j];
        r[jj] = bf_rne(dn * fmaxf(acc, 0.f));
    }
    uint4 pk;
    pk.x = r[0] | (r[1] << 16); pk.y = r[2] | (r[3] << 16);
    pk.z = r[4] | (r[5] << 16); pk.w = r[6] | (r[7] << 16);
    ((uint4*)y2b)[(size_t)(vbase + nl) * 4 + q] = pk;
}

// ---- agg(32-dim, bf16 rows) -> fp16 a3 -------------------------------------
// 4 lanes/node, each lane one uint4 (8 bf16) chunk; 2-way unrolled.
// R10: output fp16 (16B/lane) -> halves write traffic + t3fc fetch.
__global__ void __launch_bounds__(256)
agg_bf16_kernel(const unsigned int* __restrict__ y2b, const int* __restrict__ off,
                const int* __restrict__ adj, const float* __restrict__ dinv,
                _Float16* __restrict__ a3out, int n) {
    int t = blockIdx.x * 256 + threadIdx.x;
    int v = t >> 2, c = t & 3;
    if (v >= n) return;
    const uint4* yb = (const uint4*)y2b;
    uint4 us = yb[(size_t)v * 4 + c];   // self
    float p0 = bf_lo(us.x), p1 = bf_hi(us.x), p2 = bf_lo(us.y), p3 = bf_hi(us.y);
    float p4 = bf_lo(us.z), p5 = bf_hi(us.z), p6 = bf_lo(us.w), p7 = bf_hi(us.w);
    float q0 = 0, q1 = 0, q2 = 0, q3 = 0, q4 = 0, q5 = 0, q6 = 0, q7 = 0;
    int beg = off[v], end = off[v + 1];
    int e = beg;
    for (; e + 2 <= end; e += 2) {
        int s0 = adj[e], s1 = adj[e + 1];
        uint4 u0 = yb[(size_t)s0 * 4 + c];
        uint4 u1 = yb[(size_t)s1 * 4 + c];
        p0 += bf_lo(u0.x); p1 += bf_hi(u0.x); p2 += bf_lo(u0.y); p3 += bf_hi(u0.y);
        p4 += bf_lo(u0.z); p5 += bf_hi(u0.z); p6 += bf_lo(u0.w); p7 += bf_hi(u0.w);
        q0 += bf_lo(u1.x); q1 += bf_hi(u1.x); q2 += bf_lo(u1.y); q3 += bf_hi(u1.y);
        q4 += bf_lo(u1.z); q5 += bf_hi(u1.z); q6 += bf_lo(u1.w); q7 += bf_hi(u1.w);
    }
    if (e < end) {
        uint4 u0 = yb[(size_t)adj[e] * 4 + c];
        p0 += bf_lo(u0.x); p1 += bf_hi(u0.x); p2 += bf_lo(u0.y); p3 += bf_hi(u0.y);
        p4 += bf_lo(u0.z); p5 += bf_hi(u0.z); p6 += bf_lo(u0.w); p7 += bf_hi(u0.w);
    }
    float dv = dinv[v];
    uint4 st;
    st.x = pkh((p0 + q0) * dv, (p1 + q1) * dv);
    st.y = pkh((p2 + q2) * dv, (p3 + q3) * dv);
    st.z = pkh((p4 + q4) * dv, (p5 + q5) * dv);
    st.w = pkh((p6 + q6) * dv, (p7 + q7) * dv);
    ((uint4*)a3out)[(size_t)v * 4 + c] = st;
}

// ---- Fused layer-3 transform + FC via MFMA ---------------------------------
// 256 threads = 4 waves, 64 nodes/block (16 per wave).  No __syncthreads:
// B-frags come straight from global (frag-ordered fp16, L1-hot), the only
// LDS is a per-wave 2KB frag-ordered relu(t) scratch (contiguous 16B/lane
// reads -> conflict-free).  Intra-wave LDS dep: compiler-inserted lgkmcnt.
__global__ void __launch_bounds__(256)
t3fc_kernel(const _Float16* __restrict__ a3h,
            const _Float16* __restrict__ w3f, const float* __restrict__ b3,
            const _Float16* __restrict__ wff, const float* __restrict__ bf,
            float* __restrict__ out) {
    __shared__ __align__(16) _Float16 tA[4][1024];   // [wave][ks*512 + row*32 + h*8 + e]
    const int tid = threadIdx.x;
    const int w = tid >> 6, l = tid & 63;
    const int lr = l & 15, lh = l >> 4;
    const int vbase = blockIdx.x * 64 + w * 16;
    const int fragoff = lr * 32 + lh * 8;

    // A1: node row = vbase+lr, k = lh*8..lh*8+7 (fp16, 16B/lane)
    half8 A1 = *(const half8*)(a3h + (size_t)(vbase + lr) * 32 + lh * 8);

    // GEMM1: 4 col-tiles, K=32 in one MFMA each
    float4v c1[4];
#pragma unroll
    for (int nt = 0; nt < 4; nt++) {
        float bv = b3[nt * 16 + lr];                  // D col = nt*16+lr
        float4v ci = {bv, bv, bv, bv};
        half8 B = *(const half8*)(w3f + nt * 512 + fragoff);
        c1[nt] = __builtin_amdgcn_mfma_f32_16x16x32_f16(A1, B, ci, 0, 0, 0);
    }

    // relu -> fp16 -> per-wave frag-ordered scratch.
    // D elem (row = lh*4+r, col = nt*16+lr) becomes t[row][k2=col]:
    //   idx = (k2>>5)*512 + row*32 + ((k2>>3)&3)*8 + (k2&7)
    _Float16* tw = tA[w];
#pragma unroll
    for (int nt = 0; nt < 4; nt++) {
        int k2 = nt * 16 + lr;
        int base = (k2 >> 5) * 512 + ((k2 >> 3) & 3) * 8 + (k2 & 7);
#pragma unroll
        for (int r = 0; r < 4; r++)
            tw[base + (lh * 4 + r) * 32] = (_Float16)fmaxf(c1[nt][r], 0.f);
    }

    // GEMM2: K=64 = 2 k-steps x 4 col-tiles
    float4v c2[4];
#pragma unroll
    for (int nt = 0; nt < 4; nt++) {
        float bv = bf[nt * 16 + lr];
        c2[nt] = (float4v){bv, bv, bv, bv};
    }
#pragma unroll
    for (int ks = 0; ks < 2; ks++) {
        half8 A2 = *(const half8*)(tw + ks * 512 + fragoff);
#pragma unroll
        for (int nt = 0; nt < 4; nt++) {
            half8 B = *(const half8*)(wff + (ks * 4 + nt) * 512 + fragoff);
            c2[nt] = __builtin_amdgcn_mfma_f32_16x16x32_f16(A2, B, c2[nt], 0, 0, 0);
        }
    }

    // store: D elem (row = lh*4+r, col = nt*16+lr); 64B segments per (nt,r)
#pragma unroll
    for (int nt = 0; nt < 4; nt++) {
#pragma unroll
        for (int r = 0; r < 4; r++)
            out[(size_t)(vbase + lh * 4 + r) * 64 + nt * 16 + lr] = c2[nt][r];
    }
}

extern "C" void kernel_launch(void* const* d_in, const int* in_sizes, int n_in,
                              void* d_out, int out_size, void* d_ws, size_t ws_size,
                              hipStream_t stream) {
    const float* x  = (const float*)d_in[0];
    const float* W1 = (const float*)d_in[1];
    const float* b1 = (const float*)d_in[2];
    const float* W2 = (const float*)d_in[3];
    const float* b2 = (const float*)d_in[4];
    const float* W3 = (const float*)d_in[5];
    const float* b3 = (const float*)d_in[6];
    const float* Wf = (const float*)d_in[7];
    const float* bf = (const float*)d_in[8];
    const int*   ei = (const int*)d_in[9];

    const int N = in_sizes[0] / 8;   // 262144
    const int E = in_sizes[9] / 2;   // 2097152
    const int* srcv = ei;
    const int* dstv = ei + E;
    const int shift = 10;            // log2(NPB)

    // Workspace layout (16B-aligned chunks)
    char* p = (char*)d_ws;
    auto take = [&p](size_t bytes) { char* q = p; p += (bytes + 63) & ~size_t(63); return q; };
    int*   off   = (int*)take((size_t)(N + 16) * 4);
    float* dinv  = (float*)take((size_t)N * 4);
    int*   adj   = (int*)take((size_t)E * 4);
    int*   ghist = (int*)take(NB * 4);
    int*   bbase = (int*)take((NB + 1) * 4);
    int*   gcur  = (int*)take(NB * 4);
    _Float16* w3f = (_Float16*)take(32 * 64 * 2);      // frag-ordered fp16 W3
    _Float16* wff = (_Float16*)take(64 * 64 * 2);      // frag-ordered fp16 Wf
    float* bufA  = (float*)take((size_t)N * 32 * 4);   // y0 [0,8MB) then a3h (fp16, 16MB)
    float* y1    = (float*)take((size_t)N * 16 * 4);   // 16MB
    char*  regX  = take((size_t)N * 32 * 2);           // 16MB: bedge (8MB) then y2b
    unsigned int* bedge = (unsigned int*)regX;
    unsigned int* y2b   = (unsigned int*)regX;
    float* y0 = bufA;
    _Float16* a3h = (_Float16*)bufA;

    hipMemsetAsync(ghist, 0, NB * 4, stream);

    int nt = (E + TILE - 1) / TILE;  // 512 tiles
    hist_kernel<<<nt, 256, 0, stream>>>(dstv, ghist, E, shift);
    bscan_kernel<<<1, NB, 0, stream>>>(ghist, bbase, gcur, W3, Wf, w3f, wff);
    partition_kernel<<<nt, 256, 0, stream>>>(srcv, dstv, gcur, bedge, E, shift, NPB - 1);
    build_kernel<<<NB, 256, 0, stream>>>(bbase, bedge, x, off, dinv, adj, y0);

    // L1: agg(y0) + transform 8->16 -> y1
    aggt1_kernel<<<N / 128, 256, 0, stream>>>(y0, off, adj, dinv, W1, b1, y1);
    // L2: agg(y1) + transform 16->32 -> y2b (bf16; overwrites dead bedge)
    aggt2_kernel<<<N / 64, 256, 0, stream>>>(y1, off, adj, dinv, W2, b2, y2b);
    // L3: agg(y2b) -> a3h (fp16, in bufA; y0 dead), then MFMA transform+FC -> out
    agg_bf16_kernel<<<(N * 4) / 256, 256, 0, stream>>>(y2b, off, adj, dinv, a3h, N);
    t3fc_kernel<<<N / 64, 256, 0, stream>>>(a3h, w3f, b3, wff, bf, (float*)d_out);
}

// Round 5
// 290.409 us; speedup vs baseline: 1.3142x; 1.0554x over previous
//
#include <hip/hip_runtime.h>
#include <hip/hip_bf16.h>

// GCN x3 + FC on a fixed random graph.
//   1. Bucket-partition CSR build: hist -> scan -> packed partition
//      (src|dl<<18) -> per-bucket build (LDS atomics, coalesced I/O) with
//      fused prescale y0 = dinv*x (fp16, R12).
//   2. Pull aggregation over pre-scaled features y = dinv*h:
//      out[v] = dinv[v]*(sum y[s] + y[v]).  Transform fused into agg epilogue
//      via per-block LDS staging (aggt1: 8->16, aggt2: 16->32).
//   3. R12: ALL inter-layer features fp16.  Aggs are gather-latency/L2-
//      capacity bound (R11 profile: aggt2 FETCH=117MB ~= E*64B, 12% L2 hit,
//      VALUBusy 21%).  fp16 halves row footprints: y0 8->4MB (~L2-resident
//      per XCD), y1 16->8MB (~50% hit), y2 bf16->fp16 (same 16MB, +3
//      mantissa bits -> removes the 2^-7 bf16 error floor, paying for fp16
//      upstream).  Accumulation stays fp32; unpack via v_cvt_f32_f16 (free
//      at 21% VALUBusy).
//   4. t3fc (R10): MFMA mfma_f32_16x16x32_f16; weights pre-converted to
//      B-frag-ordered fp16 in bscan; no barriers; per-wave 2KB LDS relu
//      scratch.  Frag maps (m89-verified): A row=l&15, k=(l>>4)*8+j;
//      B col=l&15 same k; D col=l&15, row=(l>>4)*4+reg.

#define NB   256     // dst buckets
#define NPB  1024    // nodes per bucket (N = NB*NPB)
#define TILE 4096    // edges per partition tile
#define SRCMASK 0x3FFFFu

typedef _Float16 half8 __attribute__((ext_vector_type(8)));
typedef float float4v __attribute__((ext_vector_type(4)));

__device__ __forceinline__ unsigned pkh(float a, float b) {  // 2x fp32 -> packed fp16 (RNE)
    unsigned short ua = __builtin_bit_cast(unsigned short, (_Float16)a);
    unsigned short ub = __builtin_bit_cast(unsigned short, (_Float16)b);
    return (unsigned)ua | ((unsigned)ub << 16);
}
__device__ __forceinline__ float h_lo(unsigned u) {
    return (float)__builtin_bit_cast(_Float16, (unsigned short)(u & 0xFFFFu));
}
__device__ __forceinline__ float h_hi(unsigned u) {
    return (float)__builtin_bit_cast(_Float16, (unsigned short)(u >> 16));
}

// ---- P1: global bucket histogram -------------------------------------------
__global__ void hist_kernel(const int* __restrict__ dst, int* __restrict__ ghist,
                            int E, int shift) {
    __shared__ int h[NB];
    int tid = threadIdx.x;
    h[tid] = 0;
    __syncthreads();
    int base = blockIdx.x * TILE;
    int cnt = min(TILE, E - base);
    for (int i = tid; i < cnt; i += 256)
        atomicAdd(&h[dst[base + i] >> shift], 1);
    __syncthreads();
    int v = h[tid];
    if (v) atomicAdd(&ghist[tid], v);
}

// ---- P2: scan bucket counts + fused weight->fp16 frag conversion -----------
// Frag order for B of mfma_f32_16x16x32_f16: dest[( (k>>5)*4 + (j>>4) )*512
//  + (j&15)*32 + ((k>>3)&3)*8 + (k&7)]  (j = col, k = row of W[k][j]).
__global__ void bscan_kernel(const int* __restrict__ ghist, int* __restrict__ bbase,
                             int* __restrict__ gcursor,
                             const float* __restrict__ W3, const float* __restrict__ Wf,
                             _Float16* __restrict__ w3f, _Float16* __restrict__ wff) {
    __shared__ int sh[NB];
    int tid = threadIdx.x;
    int v = ghist[tid];
    sh[tid] = v;
    __syncthreads();
    for (int o = 1; o < NB; o <<= 1) {
        int t = (tid >= o) ? sh[tid - o] : 0;
        __syncthreads();
        sh[tid] += t;
        __syncthreads();
    }
    int incl = sh[tid];
    bbase[tid] = incl - v;
    gcursor[tid] = incl - v;
    if (tid == NB - 1) bbase[NB] = incl;
    // W3: [32][64]
    for (int i = tid; i < 32 * 64; i += NB) {
        int k = i >> 6, j = i & 63;
        w3f[(j >> 4) * 512 + (j & 15) * 32 + (k >> 3) * 8 + (k & 7)] = (_Float16)W3[i];
    }
    // Wf: [64][64]
    for (int i = tid; i < 64 * 64; i += NB) {
        int k = i >> 6, j = i & 63;
        wff[((k >> 5) * 4 + (j >> 4)) * 512 + (j & 15) * 32 + ((k >> 3) & 3) * 8 + (k & 7)]
            = (_Float16)Wf[i];
    }
}

// ---- P3: partition edges into bucket-contiguous packed stream --------------
__global__ void __launch_bounds__(256)
partition_kernel(const int* __restrict__ src, const int* __restrict__ dst,
                 int* __restrict__ gcursor, unsigned int* __restrict__ bedge,
                 int E, int shift, int mask) {
    __shared__ int h[NB], st[NB], gp[NB];
    __shared__ unsigned short rk[TILE];
    __shared__ int sd[TILE];
    __shared__ int ss[TILE];
    int tid = threadIdx.x;
    h[tid] = 0;
    __syncthreads();
    int base = blockIdx.x * TILE;
    int cnt = min(TILE, E - base);
    for (int i = tid; i < cnt; i += 256)
        rk[i] = (unsigned short)atomicAdd(&h[dst[base + i] >> shift], 1);
    __syncthreads();
    int hv = h[tid];
    st[tid] = hv;
    __syncthreads();
    for (int o = 1; o < NB; o <<= 1) {
        int t = (tid >= o) ? st[tid - o] : 0;
        __syncthreads();
        st[tid] += t;
        __syncthreads();
    }
    st[tid] -= hv;
    gp[tid] = hv ? atomicAdd(&gcursor[tid], hv) : 0;
    __syncthreads();
    for (int i = tid; i < cnt; i += 256) {
        int d = dst[base + i];
        int b = d >> shift;
        int pos = st[b] + rk[i];
        sd[pos] = d;
        ss[pos] = src[base + i];
    }
    __syncthreads();
    for (int i = tid; i < cnt; i += 256) {
        int d = sd[i];
        int b = d >> shift;
        int g = gp[b] + (i - st[b]);
        bedge[g] = (unsigned int)ss[i] | ((unsigned int)(d & mask) << 18);
    }
}

// ---- P4: per-bucket CSR build + fused prescale (fp16 y0) -------------------
__global__ void __launch_bounds__(256)
build_kernel(const int* __restrict__ bbase, const unsigned int* __restrict__ bedge,
             const float* __restrict__ x,
             int* __restrict__ off, float* __restrict__ dinv, int* __restrict__ adj,
             _Float16* __restrict__ y0h) {
    __shared__ int deg1[NPB];
    __shared__ int cur[NPB];
    __shared__ int bs[256];
    int tid = threadIdx.x;
    int b = blockIdx.x;
    int s = bbase[b], e = bbase[b + 1];
    int base = tid * 4;
#pragma unroll
    for (int i = 0; i < 4; i++) deg1[base + i] = 0;
    __syncthreads();
    for (int i = s + tid; i < e; i += 256)
        atomicAdd(&deg1[bedge[i] >> 18], 1);
    __syncthreads();
    int d0 = deg1[base], d1 = deg1[base + 1], d2 = deg1[base + 2], d3 = deg1[base + 3];
    int th = d0 + d1 + d2 + d3;
    bs[tid] = th;
    __syncthreads();
    for (int o = 1; o < 256; o <<= 1) {
        int t = (tid >= o) ? bs[tid - o] : 0;
        __syncthreads();
        bs[tid] += t;
        __syncthreads();
    }
    int run = s + bs[tid] - th;
    int vb = b * NPB + base;
    off[vb]     = run; cur[base]     = run; dinv[vb]     = rsqrtf((float)(d0 + 1)); run += d0;
    off[vb + 1] = run; cur[base + 1] = run; dinv[vb + 1] = rsqrtf((float)(d1 + 1)); run += d1;
    off[vb + 2] = run; cur[base + 2] = run; dinv[vb + 2] = rsqrtf((float)(d2 + 1)); run += d2;
    off[vb + 3] = run; cur[base + 3] = run; dinv[vb + 3] = rsqrtf((float)(d3 + 1)); run += d3;
    if (b == NB - 1 && tid == 255) off[NB * NPB] = e;   // sentinel off[N] = E
    __syncthreads();
    for (int i = s + tid; i < e; i += 256) {
        unsigned int pk = bedge[i];
        int p = atomicAdd(&cur[pk >> 18], 1);
        adj[p] = (int)(pk & SRCMASK);
    }
    // fused prescale: y0h[v] = fp16(dinv[v] * x[v])  (bucket rows, coalesced)
    for (int i = tid; i < NPB; i += 256) {
        float dv = rsqrtf((float)(deg1[i] + 1));
        const float4* xr = (const float4*)x + (size_t)(b * NPB + i) * 2;
        float4 t0 = xr[0], t1 = xr[1];
        uint4 pk;
        pk.x = pkh(t0.x * dv, t0.y * dv); pk.y = pkh(t0.z * dv, t0.w * dv);
        pk.z = pkh(t1.x * dv, t1.y * dv); pk.w = pkh(t1.z * dv, t1.w * dv);
        ((uint4*)y0h)[(size_t)b * NPB + i] = pk;
    }
}

// ---- Fused agg(8-dim fp16) + transform 8->16 -> fp16 y1 --------------------
// gather: 2 lanes/node, uint2 (4 fp16) each; fp32 accumulate.
__global__ void __launch_bounds__(256)
aggt1_kernel(const _Float16* __restrict__ y0h, const int* __restrict__ off,
             const int* __restrict__ adj, const float* __restrict__ dinv,
             const float* __restrict__ W1, const float* __restrict__ b1,
             _Float16* __restrict__ y1h) {
    __shared__ float Ws[8 * 16];
    __shared__ float bsh[16];
    __shared__ float sh[128][9];
    const int tid = threadIdx.x;
    if (tid < 128) Ws[tid] = W1[tid];
    if (tid < 16) bsh[tid] = b1[tid];
    const int vbase = blockIdx.x * 128;
    const int vl = tid >> 1, c = tid & 1;
    const int vg = vbase + vl;
    const uint2* y2 = (const uint2*)y0h;
    int beg = off[vg];
    int end = off[vg + 1];
    uint2 us = y2[(size_t)vg * 2 + c];   // self
    float a0x = h_lo(us.x), a0y = h_hi(us.x), a0z = h_lo(us.y), a0w = h_hi(us.y);
    float a1x = 0, a1y = 0, a1z = 0, a1w = 0;
    float a2x = 0, a2y = 0, a2z = 0, a2w = 0;
    float a3x = 0, a3y = 0, a3z = 0, a3w = 0;
    int e = beg;
    for (; e + 4 <= end; e += 4) {
        int s0 = adj[e], s1 = adj[e + 1], s2 = adj[e + 2], s3 = adj[e + 3];
        uint2 u0 = y2[(size_t)s0 * 2 + c];
        uint2 u1 = y2[(size_t)s1 * 2 + c];
        uint2 u2 = y2[(size_t)s2 * 2 + c];
        uint2 u3 = y2[(size_t)s3 * 2 + c];
        a0x += h_lo(u0.x); a0y += h_hi(u0.x); a0z += h_lo(u0.y); a0w += h_hi(u0.y);
        a1x += h_lo(u1.x); a1y += h_hi(u1.x); a1z += h_lo(u1.y); a1w += h_hi(u1.y);
        a2x += h_lo(u2.x); a2y += h_hi(u2.x); a2z += h_lo(u2.y); a2w += h_hi(u2.y);
        a3x += h_lo(u3.x); a3y += h_hi(u3.x); a3z += h_lo(u3.y); a3w += h_hi(u3.y);
    }
    for (; e < end; e++) {
        uint2 u0 = y2[(size_t)adj[e] * 2 + c];
        a1x += h_lo(u0.x); a1y += h_hi(u0.x); a1z += h_lo(u0.y); a1w += h_hi(u0.y);
    }
    float dv = dinv[vg];
    sh[vl][c * 4 + 0] = ((a0x + a1x) + (a2x + a3x)) * dv;
    sh[vl][c * 4 + 1] = ((a0y + a1y) + (a2y + a3y)) * dv;
    sh[vl][c * 4 + 2] = ((a0z + a1z) + (a2z + a3z)) * dv;
    sh[vl][c * 4 + 3] = ((a0w + a1w) + (a2w + a3w)) * dv;
    __syncthreads();
    // transform: thread -> (node nl, half hf), 8 outputs, pack fp16
    const int nl = tid & 127, hf = tid >> 7, j0 = hf * 8;
    float in0 = sh[nl][0], in1 = sh[nl][1], in2 = sh[nl][2], in3 = sh[nl][3];
    float in4 = sh[nl][4], in5 = sh[nl][5], in6 = sh[nl][6], in7 = sh[nl][7];
    float dn = dinv[vbase + nl];
    float o[8];
#pragma unroll
    for (int jj = 0; jj < 8; jj++) {
        int j = j0 + jj;
        float acc = bsh[j];
        acc += in0 * Ws[0 * 16 + j]; acc += in1 * Ws[1 * 16 + j];
        acc += in2 * Ws[2 * 16 + j]; acc += in3 * Ws[3 * 16 + j];
        acc += in4 * Ws[4 * 16 + j]; acc += in5 * Ws[5 * 16 + j];
        acc += in6 * Ws[6 * 16 + j]; acc += in7 * Ws[7 * 16 + j];
        o[jj] = dn * fmaxf(acc, 0.f);
    }
    uint4 pk;
    pk.x = pkh(o[0], o[1]); pk.y = pkh(o[2], o[3]);
    pk.z = pkh(o[4], o[5]); pk.w = pkh(o[6], o[7]);
    ((uint4*)y1h)[(size_t)(vbase + nl) * 2 + hf] = pk;
}

// ---- Fused agg(16-dim fp16) + transform 16->32 -> fp16 y2 ------------------
// gather: 4 lanes/node, uint2 (4 fp16) each; fp32 accumulate.
__global__ void __launch_bounds__(256)
aggt2_kernel(const _Float16* __restrict__ y1h, const int* __restrict__ off,
             const int* __restrict__ adj, const float* __restrict__ dinv,
             const float* __restrict__ W2, const float* __restrict__ b2,
             unsigned int* __restrict__ y2b) {
    __shared__ float Ws[16 * 32];
    __shared__ float bsh[32];
    __shared__ float sh[64][17];
    const int tid = threadIdx.x;
    for (int i = tid; i < 16 * 32; i += 256) Ws[i] = W2[i];
    if (tid < 32) bsh[tid] = b2[tid];
    const int vbase = blockIdx.x * 64;
    const int vl = tid >> 2, c = tid & 3;
    const int vg = vbase + vl;
    const uint2* y2 = (const uint2*)y1h;
    int beg = off[vg];
    int end = off[vg + 1];
    uint2 us = y2[(size_t)vg * 4 + c];   // self
    float a0x = h_lo(us.x), a0y = h_hi(us.x), a0z = h_lo(us.y), a0w = h_hi(us.y);
    float a1x = 0, a1y = 0, a1z = 0, a1w = 0;
    float a2x = 0, a2y = 0, a2z = 0, a2w = 0;
    float a3x = 0, a3y = 0, a3z = 0, a3w = 0;
    int e = beg;
    for (; e + 4 <= end; e += 4) {
        int s0 = adj[e], s1 = adj[e + 1], s2 = adj[e + 2], s3 = adj[e + 3];
        uint2 u0 = y2[(size_t)s0 * 4 + c];
        uint2 u1 = y2[(size_t)s1 * 4 + c];
        uint2 u2 = y2[(size_t)s2 * 4 + c];
        uint2 u3 = y2[(size_t)s3 * 4 + c];
        a0x += h_lo(u0.x); a0y += h_hi(u0.x); a0z += h_lo(u0.y); a0w += h_hi(u0.y);
        a1x += h_lo(u1.x); a1y += h_hi(u1.x); a1z += h_lo(u1.y); a1w += h_hi(u1.y);
        a2x += h_lo(u2.x); a2y += h_hi(u2.x); a2z += h_lo(u2.y); a2w += h_hi(u2.y);
        a3x += h_lo(u3.x); a3y += h_hi(u3.x); a3z += h_lo(u3.y); a3w += h_hi(u3.y);
    }
    for (; e < end; e++) {
        uint2 u0 = y2[(size_t)adj[e] * 4 + c];
        a1x += h_lo(u0.x); a1y += h_hi(u0.x); a1z += h_lo(u0.y); a1w += h_hi(u0.y);
    }
    float dv = dinv[vg];
    sh[vl][c * 4 + 0] = ((a0x + a1x) + (a2x + a3x)) * dv;
    sh[vl][c * 4 + 1] = ((a0y + a1y) + (a2y + a3y)) * dv;
    sh[vl][c * 4 + 2] = ((a0z + a1z) + (a2z + a3z)) * dv;
    sh[vl][c * 4 + 3] = ((a0w + a1w) + (a2w + a3w)) * dv;
    __syncthreads();
    // transform: thread -> (node nl, quarter q), 8 outputs, pack fp16
    const int nl = tid & 63, q = tid >> 6, j0 = q * 8;
    float in[16];
#pragma unroll
    for (int k = 0; k < 16; k++) in[k] = sh[nl][k];
    float dn = dinv[vbase + nl];
    float o[8];
#pragma unroll
    for (int jj = 0; jj < 8; jj++) {
        int j = j0 + jj;
        float acc = bsh[j];
#pragma unroll
        for (int k = 0; k < 16; k++) acc += in[k] * Ws[k * 32 + j];
        o[jj] = dn * fmaxf(acc, 0.f);
    }
    uint4 pk;
    pk.x = pkh(o[0], o[1]); pk.y = pkh(o[2], o[3]);
    pk.z = pkh(o[4], o[5]); pk.w = pkh(o[6], o[7]);
    ((uint4*)y2b)[(size_t)(vbase + nl) * 4 + q] = pk;
}

// ---- agg(32-dim, fp16 rows) -> fp16 a3 -------------------------------------
// 4 lanes/node, each lane one uint4 (8 fp16) chunk; 2-way unrolled.
__global__ void __launch_bounds__(256)
agg3_kernel(const unsigned int* __restrict__ y2b, const int* __restrict__ off,
            const int* __restrict__ adj, const float* __restrict__ dinv,
            _Float16* __restrict__ a3out, int n) {
    int t = blockIdx.x * 256 + threadIdx.x;
    int v = t >> 2, c = t & 3;
    if (v >= n) return;
    const uint4* yb = (const uint4*)y2b;
    uint4 us = yb[(size_t)v * 4 + c];   // self
    float p0 = h_lo(us.x), p1 = h_hi(us.x), p2 = h_lo(us.y), p3 = h_hi(us.y);
    float p4 = h_lo(us.z), p5 = h_hi(us.z), p6 = h_lo(us.w), p7 = h_hi(us.w);
    float q0 = 0, q1 = 0, q2 = 0, q3 = 0, q4 = 0, q5 = 0, q6 = 0, q7 = 0;
    int beg = off[v], end = off[v + 1];
    int e = beg;
    for (; e + 2 <= end; e += 2) {
        int s0 = adj[e], s1 = adj[e + 1];
        uint4 u0 = yb[(size_t)s0 * 4 + c];
        uint4 u1 = yb[(size_t)s1 * 4 + c];
        p0 += h_lo(u0.x); p1 += h_hi(u0.x); p2 += h_lo(u0.y); p3 += h_hi(u0.y);
        p4 += h_lo(u0.z); p5 += h_hi(u0.z); p6 += h_lo(u0.w); p7 += h_hi(u0.w);
        q0 += h_lo(u1.x); q1 += h_hi(u1.x); q2 += h_lo(u1.y); q3 += h_hi(u1.y);
        q4 += h_lo(u1.z); q5 += h_hi(u1.z); q6 += h_lo(u1.w); q7 += h_hi(u1.w);
    }
    if (e < end) {
        uint4 u0 = yb[(size_t)adj[e] * 4 + c];
        p0 += h_lo(u0.x); p1 += h_hi(u0.x); p2 += h_lo(u0.y); p3 += h_hi(u0.y);
        p4 += h_lo(u0.z); p5 += h_hi(u0.z); p6 += h_lo(u0.w); p7 += h_hi(u0.w);
    }
    float dv = dinv[v];
    uint4 st;
    st.x = pkh((p0 + q0) * dv, (p1 + q1) * dv);
    st.y = pkh((p2 + q2) * dv, (p3 + q3) * dv);
    st.z = pkh((p4 + q4) * dv, (p5 + q5) * dv);
    st.w = pkh((p6 + q6) * dv, (p7 + q7) * dv);
    ((uint4*)a3out)[(size_t)v * 4 + c] = st;
}

// ---- Fused layer-3 transform + FC via MFMA ---------------------------------
// 256 threads = 4 waves, 64 nodes/block (16 per wave).  No __syncthreads:
// B-frags come straight from global (frag-ordered fp16, L1-hot), the only
// LDS is a per-wave 2KB frag-ordered relu(t) scratch (contiguous 16B/lane
// reads -> conflict-free).  Intra-wave LDS dep: compiler-inserted lgkmcnt.
__global__ void __launch_bounds__(256)
t3fc_kernel(const _Float16* __restrict__ a3h,
            const _Float16* __restrict__ w3f, const float* __restrict__ b3,
            const _Float16* __restrict__ wff, const float* __restrict__ bf,
            float* __restrict__ out) {
    __shared__ __align__(16) _Float16 tA[4][1024];   // [wave][ks*512 + row*32 + h*8 + e]
    const int tid = threadIdx.x;
    const int w = tid >> 6, l = tid & 63;
    const int lr = l & 15, lh = l >> 4;
    const int vbase = blockIdx.x * 64 + w * 16;
    const int fragoff = lr * 32 + lh * 8;

    // A1: node row = vbase+lr, k = lh*8..lh*8+7 (fp16, 16B/lane)
    half8 A1 = *(const half8*)(a3h + (size_t)(vbase + lr) * 32 + lh * 8);

    // GEMM1: 4 col-tiles, K=32 in one MFMA each
    float4v c1[4];
#pragma unroll
    for (int nt = 0; nt < 4; nt++) {
        float bv = b3[nt * 16 + lr];                  // D col = nt*16+lr
        float4v ci = {bv, bv, bv, bv};
        half8 B = *(const half8*)(w3f + nt * 512 + fragoff);
        c1[nt] = __builtin_amdgcn_mfma_f32_16x16x32_f16(A1, B, ci, 0, 0, 0);
    }

    // relu -> fp16 -> per-wave frag-ordered scratch.
    // D elem (row = lh*4+r, col = nt*16+lr) becomes t[row][k2=col]:
    //   idx = (k2>>5)*512 + row*32 + ((k2>>3)&3)*8 + (k2&7)
    _Float16* tw = tA[w];
#pragma unroll
    for (int nt = 0; nt < 4; nt++) {
        int k2 = nt * 16 + lr;
        int base = (k2 >> 5) * 512 + ((k2 >> 3) & 3) * 8 + (k2 & 7);
#pragma unroll
        for (int r = 0; r < 4; r++)
            tw[base + (lh * 4 + r) * 32] = (_Float16)fmaxf(c1[nt][r], 0.f);
    }

    // GEMM2: K=64 = 2 k-steps x 4 col-tiles
    float4v c2[4];
#pragma unroll
    for (int nt = 0; nt < 4; nt++) {
        float bv = bf[nt * 16 + lr];
        c2[nt] = (float4v){bv, bv, bv, bv};
    }
#pragma unroll
    for (int ks = 0; ks < 2; ks++) {
        half8 A2 = *(const half8*)(tw + ks * 512 + fragoff);
#pragma unroll
        for (int nt = 0; nt < 4; nt++) {
            half8 B = *(const half8*)(wff + (ks * 4 + nt) * 512 + fragoff);
            c2[nt] = __builtin_amdgcn_mfma_f32_16x16x32_f16(A2, B, c2[nt], 0, 0, 0);
        }
    }

    // store: D elem (row = lh*4+r, col = nt*16+lr); 64B segments per (nt,r)
#pragma unroll
    for (int nt = 0; nt < 4; nt++) {
#pragma unroll
        for (int r = 0; r < 4; r++)
            out[(size_t)(vbase + lh * 4 + r) * 64 + nt * 16 + lr] = c2[nt][r];
    }
}

extern "C" void kernel_launch(void* const* d_in, const int* in_sizes, int n_in,
                              void* d_out, int out_size, void* d_ws, size_t ws_size,
                              hipStream_t stream) {
    const float* x  = (const float*)d_in[0];
    const float* W1 = (const float*)d_in[1];
    const float* b1 = (const float*)d_in[2];
    const float* W2 = (const float*)d_in[3];
    const float* b2 = (const float*)d_in[4];
    const float* W3 = (const float*)d_in[5];
    const float* b3 = (const float*)d_in[6];
    const float* Wf = (const float*)d_in[7];
    const float* bf = (const float*)d_in[8];
    const int*   ei = (const int*)d_in[9];

    const int N = in_sizes[0] / 8;   // 262144
    const int E = in_sizes[9] / 2;   // 2097152
    const int* srcv = ei;
    const int* dstv = ei + E;
    const int shift = 10;            // log2(NPB)

    // Workspace layout (16B-aligned chunks)
    char* p = (char*)d_ws;
    auto take = [&p](size_t bytes) { char* q = p; p += (bytes + 63) & ~size_t(63); return q; };
    int*   off   = (int*)take((size_t)(N + 16) * 4);
    float* dinv  = (float*)take((size_t)N * 4);
    int*   adj   = (int*)take((size_t)E * 4);
    int*   ghist = (int*)take(NB * 4);
    int*   bbase = (int*)take((NB + 1) * 4);
    int*   gcur  = (int*)take(NB * 4);
    _Float16* w3f = (_Float16*)take(32 * 64 * 2);      // frag-ordered fp16 W3
    _Float16* wff = (_Float16*)take(64 * 64 * 2);      // frag-ordered fp16 Wf
    char*  bufA  = take((size_t)N * 32 * 4);           // y0h (4MB) then a3h (fp16, 16MB)
    char*  bufB  = take((size_t)N * 16 * 4);           // y1h (fp16, 8MB)
    char*  regX  = take((size_t)N * 32 * 2);           // 16MB: bedge (8MB) then y2b (fp16)
    unsigned int* bedge = (unsigned int*)regX;
    unsigned int* y2b   = (unsigned int*)regX;
    _Float16* y0h = (_Float16*)bufA;
    _Float16* a3h = (_Float16*)bufA;
    _Float16* y1h = (_Float16*)bufB;

    hipMemsetAsync(ghist, 0, NB * 4, stream);

    int nt = (E + TILE - 1) / TILE;  // 512 tiles
    hist_kernel<<<nt, 256, 0, stream>>>(dstv, ghist, E, shift);
    bscan_kernel<<<1, NB, 0, stream>>>(ghist, bbase, gcur, W3, Wf, w3f, wff);
    partition_kernel<<<nt, 256, 0, stream>>>(srcv, dstv, gcur, bedge, E, shift, NPB - 1);
    build_kernel<<<NB, 256, 0, stream>>>(bbase, bedge, x, off, dinv, adj, y0h);

    // L1: agg(y0h) + transform 8->16 -> y1h (fp16)
    aggt1_kernel<<<N / 128, 256, 0, stream>>>(y0h, off, adj, dinv, W1, b1, y1h);
    // L2: agg(y1h) + transform 16->32 -> y2b (fp16; overwrites dead bedge)
    aggt2_kernel<<<N / 64, 256, 0, stream>>>(y1h, off, adj, dinv, W2, b2, y2b);
    // L3: agg(y2b) -> a3h (fp16, in bufA; y0h dead), then MFMA transform+FC -> out
    agg3_kernel<<<(N * 4) / 256, 256, 0, stream>>>(y2b, off, adj, dinv, a3h, N);
    t3fc_kernel<<<N / 64, 256, 0, stream>>>(a3h, w3f, b3, wff, bf, (float*)d_out);
}

// Round 6
// 283.024 us; speedup vs baseline: 1.3485x; 1.0261x over previous
//
#include <hip/hip_runtime.h>
#include <hip/hip_bf16.h>

// GCN x3 + FC on a fixed random graph.
//   1. Bucket-partition CSR build: hist -> scan -> packed partition
//      (src|dl<<18) -> per-bucket build (LDS atomics, coalesced I/O) with
//      fused prescale y0 = dinv*x (fp16).
//   2. Pull aggregation over pre-scaled features y = dinv*h:
//      out[v] = dinv[v]*(sum y[s] + y[v]).
//   3. All inter-layer features fp16 (R12): y0 4MB, y1 8MB, y2 16MB.
//      absmax floor (2^-7) is the fp16 ulp of a3h at |a3|~8-16, not y2.
//   4. R13: agg kernels restructured for MLP + LDS-instr count (aggt2 was
//      stall-bound: 2.4 of ~4TB/s random ceiling, VALUBusy 26%, epilogue
//      did 128 scalar LDS Ws reads/thread):
//      - aggt1: 1 lane/node (full 16B row/load), 8-wide gather unroll,
//        transform fully in registers, Ws via float4.
//      - aggt2: 2 lanes/node (16B/load), 8-wide unroll, halves exchanged
//        via shfl_xor (no LDS staging), Ws via float4.
//      - agg3: 4-wide unroll.
//   5. t3fc (R10): MFMA mfma_f32_16x16x32_f16; weights pre-converted to
//      B-frag-ordered fp16 in bscan; per-wave 2KB LDS relu scratch.

#define NB   256     // dst buckets
#define NPB  1024    // nodes per bucket (N = NB*NPB)
#define TILE 4096    // edges per partition tile
#define SRCMASK 0x3FFFFu

typedef _Float16 half8 __attribute__((ext_vector_type(8)));
typedef float float4v __attribute__((ext_vector_type(4)));

__device__ __forceinline__ unsigned pkh(float a, float b) {  // 2x fp32 -> packed fp16 (RNE)
    unsigned short ua = __builtin_bit_cast(unsigned short, (_Float16)a);
    unsigned short ub = __builtin_bit_cast(unsigned short, (_Float16)b);
    return (unsigned)ua | ((unsigned)ub << 16);
}
__device__ __forceinline__ float h_lo(unsigned u) {
    return (float)__builtin_bit_cast(_Float16, (unsigned short)(u & 0xFFFFu));
}
__device__ __forceinline__ float h_hi(unsigned u) {
    return (float)__builtin_bit_cast(_Float16, (unsigned short)(u >> 16));
}

#define UNPK8_ADD(A, u) \
    A##0 += h_lo(u.x); A##1 += h_hi(u.x); A##2 += h_lo(u.y); A##3 += h_hi(u.y); \
    A##4 += h_lo(u.z); A##5 += h_hi(u.z); A##6 += h_lo(u.w); A##7 += h_hi(u.w);

// ---- P1: global bucket histogram -------------------------------------------
__global__ void hist_kernel(const int* __restrict__ dst, int* __restrict__ ghist,
                            int E, int shift) {
    __shared__ int h[NB];
    int tid = threadIdx.x;
    h[tid] = 0;
    __syncthreads();
    int base = blockIdx.x * TILE;
    int cnt = min(TILE, E - base);
    for (int i = tid; i < cnt; i += 256)
        atomicAdd(&h[dst[base + i] >> shift], 1);
    __syncthreads();
    int v = h[tid];
    if (v) atomicAdd(&ghist[tid], v);
}

// ---- P2: scan bucket counts + fused weight->fp16 frag conversion -----------
// Frag order for B of mfma_f32_16x16x32_f16: dest[( (k>>5)*4 + (j>>4) )*512
//  + (j&15)*32 + ((k>>3)&3)*8 + (k&7)]  (j = col, k = row of W[k][j]).
__global__ void bscan_kernel(const int* __restrict__ ghist, int* __restrict__ bbase,
                             int* __restrict__ gcursor,
                             const float* __restrict__ W3, const float* __restrict__ Wf,
                             _Float16* __restrict__ w3f, _Float16* __restrict__ wff) {
    __shared__ int sh[NB];
    int tid = threadIdx.x;
    int v = ghist[tid];
    sh[tid] = v;
    __syncthreads();
    for (int o = 1; o < NB; o <<= 1) {
        int t = (tid >= o) ? sh[tid - o] : 0;
        __syncthreads();
        sh[tid] += t;
        __syncthreads();
    }
    int incl = sh[tid];
    bbase[tid] = incl - v;
    gcursor[tid] = incl - v;
    if (tid == NB - 1) bbase[NB] = incl;
    // W3: [32][64]
    for (int i = tid; i < 32 * 64; i += NB) {
        int k = i >> 6, j = i & 63;
        w3f[(j >> 4) * 512 + (j & 15) * 32 + (k >> 3) * 8 + (k & 7)] = (_Float16)W3[i];
    }
    // Wf: [64][64]
    for (int i = tid; i < 64 * 64; i += NB) {
        int k = i >> 6, j = i & 63;
        wff[((k >> 5) * 4 + (j >> 4)) * 512 + (j & 15) * 32 + ((k >> 3) & 3) * 8 + (k & 7)]
            = (_Float16)Wf[i];
    }
}

// ---- P3: partition edges into bucket-contiguous packed stream --------------
__global__ void __launch_bounds__(256)
partition_kernel(const int* __restrict__ src, const int* __restrict__ dst,
                 int* __restrict__ gcursor, unsigned int* __restrict__ bedge,
                 int E, int shift, int mask) {
    __shared__ int h[NB], st[NB], gp[NB];
    __shared__ unsigned short rk[TILE];
    __shared__ int sd[TILE];
    __shared__ int ss[TILE];
    int tid = threadIdx.x;
    h[tid] = 0;
    __syncthreads();
    int base = blockIdx.x * TILE;
    int cnt = min(TILE, E - base);
    for (int i = tid; i < cnt; i += 256)
        rk[i] = (unsigned short)atomicAdd(&h[dst[base + i] >> shift], 1);
    __syncthreads();
    int hv = h[tid];
    st[tid] = hv;
    __syncthreads();
    for (int o = 1; o < NB; o <<= 1) {
        int t = (tid >= o) ? st[tid - o] : 0;
        __syncthreads();
        st[tid] += t;
        __syncthreads();
    }
    st[tid] -= hv;
    gp[tid] = hv ? atomicAdd(&gcursor[tid], hv) : 0;
    __syncthreads();
    for (int i = tid; i < cnt; i += 256) {
        int d = dst[base + i];
        int b = d >> shift;
        int pos = st[b] + rk[i];
        sd[pos] = d;
        ss[pos] = src[base + i];
    }
    __syncthreads();
    for (int i = tid; i < cnt; i += 256) {
        int d = sd[i];
        int b = d >> shift;
        int g = gp[b] + (i - st[b]);
        bedge[g] = (unsigned int)ss[i] | ((unsigned int)(d & mask) << 18);
    }
}

// ---- P4: per-bucket CSR build + fused prescale (fp16 y0) -------------------
__global__ void __launch_bounds__(256)
build_kernel(const int* __restrict__ bbase, const unsigned int* __restrict__ bedge,
             const float* __restrict__ x,
             int* __restrict__ off, float* __restrict__ dinv, int* __restrict__ adj,
             _Float16* __restrict__ y0h) {
    __shared__ int deg1[NPB];
    __shared__ int cur[NPB];
    __shared__ int bs[256];
    int tid = threadIdx.x;
    int b = blockIdx.x;
    int s = bbase[b], e = bbase[b + 1];
    int base = tid * 4;
#pragma unroll
    for (int i = 0; i < 4; i++) deg1[base + i] = 0;
    __syncthreads();
    for (int i = s + tid; i < e; i += 256)
        atomicAdd(&deg1[bedge[i] >> 18], 1);
    __syncthreads();
    int d0 = deg1[base], d1 = deg1[base + 1], d2 = deg1[base + 2], d3 = deg1[base + 3];
    int th = d0 + d1 + d2 + d3;
    bs[tid] = th;
    __syncthreads();
    for (int o = 1; o < 256; o <<= 1) {
        int t = (tid >= o) ? bs[tid - o] : 0;
        __syncthreads();
        bs[tid] += t;
        __syncthreads();
    }
    int run = s + bs[tid] - th;
    int vb = b * NPB + base;
    off[vb]     = run; cur[base]     = run; dinv[vb]     = rsqrtf((float)(d0 + 1)); run += d0;
    off[vb + 1] = run; cur[base + 1] = run; dinv[vb + 1] = rsqrtf((float)(d1 + 1)); run += d1;
    off[vb + 2] = run; cur[base + 2] = run; dinv[vb + 2] = rsqrtf((float)(d2 + 1)); run += d2;
    off[vb + 3] = run; cur[base + 3] = run; dinv[vb + 3] = rsqrtf((float)(d3 + 1)); run += d3;
    if (b == NB - 1 && tid == 255) off[NB * NPB] = e;   // sentinel off[N] = E
    __syncthreads();
    for (int i = s + tid; i < e; i += 256) {
        unsigned int pk = bedge[i];
        int p = atomicAdd(&cur[pk >> 18], 1);
        adj[p] = (int)(pk & SRCMASK);
    }
    // fused prescale: y0h[v] = fp16(dinv[v] * x[v])  (bucket rows, coalesced)
    for (int i = tid; i < NPB; i += 256) {
        float dv = rsqrtf((float)(deg1[i] + 1));
        const float4* xr = (const float4*)x + (size_t)(b * NPB + i) * 2;
        float4 t0 = xr[0], t1 = xr[1];
        uint4 pk;
        pk.x = pkh(t0.x * dv, t0.y * dv); pk.y = pkh(t0.z * dv, t0.w * dv);
        pk.z = pkh(t1.x * dv, t1.y * dv); pk.w = pkh(t1.z * dv, t1.w * dv);
        ((uint4*)y0h)[(size_t)b * NPB + i] = pk;
    }
}

// ---- Fused agg(8-dim fp16) + transform 8->16 -> fp16 y1 --------------------
// R13: 1 lane/node, full 16B row per gather, 8-wide unroll; transform fully
// in registers (no staging LDS, no barrier except Ws visibility).
__global__ void __launch_bounds__(256)
aggt1_kernel(const _Float16* __restrict__ y0h, const int* __restrict__ off,
             const int* __restrict__ adj, const float* __restrict__ dinv,
             const float* __restrict__ W1, const float* __restrict__ b1,
             _Float16* __restrict__ y1h) {
    __shared__ float Ws[8 * 16];
    __shared__ float bsh[16];
    const int tid = threadIdx.x;
    if (tid < 128) Ws[tid] = W1[tid];
    if (tid < 16) bsh[tid] = b1[tid];
    const int vg = blockIdx.x * 256 + tid;
    const uint4* y4 = (const uint4*)y0h;
    int beg = off[vg], end = off[vg + 1];
    uint4 us = y4[vg];   // self (full row)
    float a0 = h_lo(us.x), a1 = h_hi(us.x), a2 = h_lo(us.y), a3 = h_hi(us.y),
          a4 = h_lo(us.z), a5 = h_hi(us.z), a6 = h_lo(us.w), a7 = h_hi(us.w);
    float c0 = 0, c1 = 0, c2 = 0, c3 = 0, c4 = 0, c5 = 0, c6 = 0, c7 = 0;
    int e = beg;
    for (; e + 8 <= end; e += 8) {
        int s0 = adj[e], s1 = adj[e + 1], s2 = adj[e + 2], s3 = adj[e + 3];
        int s4 = adj[e + 4], s5 = adj[e + 5], s6 = adj[e + 6], s7 = adj[e + 7];
        uint4 u0 = y4[s0], u1 = y4[s1], u2 = y4[s2], u3 = y4[s3];
        uint4 u4 = y4[s4], u5 = y4[s5], u6 = y4[s6], u7 = y4[s7];
        UNPK8_ADD(a, u0) UNPK8_ADD(c, u1) UNPK8_ADD(a, u2) UNPK8_ADD(c, u3)
        UNPK8_ADD(a, u4) UNPK8_ADD(c, u5) UNPK8_ADD(a, u6) UNPK8_ADD(c, u7)
    }
    for (; e + 2 <= end; e += 2) {
        int s0 = adj[e], s1 = adj[e + 1];
        uint4 u0 = y4[s0], u1 = y4[s1];
        UNPK8_ADD(a, u0) UNPK8_ADD(c, u1)
    }
    if (e < end) {
        uint4 u0 = y4[adj[e]];
        UNPK8_ADD(a, u0)
    }
    float dv = dinv[vg];
    float in[8];
    in[0] = (a0 + c0) * dv; in[1] = (a1 + c1) * dv;
    in[2] = (a2 + c2) * dv; in[3] = (a3 + c3) * dv;
    in[4] = (a4 + c4) * dv; in[5] = (a5 + c5) * dv;
    in[6] = (a6 + c6) * dv; in[7] = (a7 + c7) * dv;
    __syncthreads();   // Ws/bsh visibility
    // transform 8->16 in registers; Ws rows as float4 (pitch 16 floats, aligned)
    const float4* W4 = (const float4*)Ws;
    float o[16];
    {
        float4 b0 = ((const float4*)bsh)[0], b1v = ((const float4*)bsh)[1];
        float4 b2v = ((const float4*)bsh)[2], b3v = ((const float4*)bsh)[3];
        o[0] = b0.x; o[1] = b0.y; o[2] = b0.z; o[3] = b0.w;
        o[4] = b1v.x; o[5] = b1v.y; o[6] = b1v.z; o[7] = b1v.w;
        o[8] = b2v.x; o[9] = b2v.y; o[10] = b2v.z; o[11] = b2v.w;
        o[12] = b3v.x; o[13] = b3v.y; o[14] = b3v.z; o[15] = b3v.w;
    }
#pragma unroll
    for (int k = 0; k < 8; k++) {
        float xk = in[k];
        float4 w0 = W4[k * 4 + 0], w1 = W4[k * 4 + 1];
        float4 w2 = W4[k * 4 + 2], w3 = W4[k * 4 + 3];
        o[0] = fmaf(xk, w0.x, o[0]);  o[1] = fmaf(xk, w0.y, o[1]);
        o[2] = fmaf(xk, w0.z, o[2]);  o[3] = fmaf(xk, w0.w, o[3]);
        o[4] = fmaf(xk, w1.x, o[4]);  o[5] = fmaf(xk, w1.y, o[5]);
        o[6] = fmaf(xk, w1.z, o[6]);  o[7] = fmaf(xk, w1.w, o[7]);
        o[8] = fmaf(xk, w2.x, o[8]);  o[9] = fmaf(xk, w2.y, o[9]);
        o[10] = fmaf(xk, w2.z, o[10]); o[11] = fmaf(xk, w2.w, o[11]);
        o[12] = fmaf(xk, w3.x, o[12]); o[13] = fmaf(xk, w3.y, o[13]);
        o[14] = fmaf(xk, w3.z, o[14]); o[15] = fmaf(xk, w3.w, o[15]);
    }
    uint4 p0, p1;
    p0.x = pkh(dv * fmaxf(o[0], 0.f),  dv * fmaxf(o[1], 0.f));
    p0.y = pkh(dv * fmaxf(o[2], 0.f),  dv * fmaxf(o[3], 0.f));
    p0.z = pkh(dv * fmaxf(o[4], 0.f),  dv * fmaxf(o[5], 0.f));
    p0.w = pkh(dv * fmaxf(o[6], 0.f),  dv * fmaxf(o[7], 0.f));
    p1.x = pkh(dv * fmaxf(o[8], 0.f),  dv * fmaxf(o[9], 0.f));
    p1.y = pkh(dv * fmaxf(o[10], 0.f), dv * fmaxf(o[11], 0.f));
    p1.z = pkh(dv * fmaxf(o[12], 0.f), dv * fmaxf(o[13], 0.f));
    p1.w = pkh(dv * fmaxf(o[14], 0.f), dv * fmaxf(o[15], 0.f));
    uint4* out4 = (uint4*)y1h;
    out4[(size_t)vg * 2]     = p0;
    out4[(size_t)vg * 2 + 1] = p1;
}

// ---- Fused agg(16-dim fp16) + transform 16->32 -> fp16 y2 ------------------
// R13: 2 lanes/node, 16B/gather, 8-wide unroll; halves exchanged via
// shfl_xor (no LDS staging); Ws as float4.  Lane c computes outputs
// j = c*16 .. c*16+15.
__global__ void __launch_bounds__(256)
aggt2_kernel(const _Float16* __restrict__ y1h, const int* __restrict__ off,
             const int* __restrict__ adj, const float* __restrict__ dinv,
             const float* __restrict__ W2, const float* __restrict__ b2,
             unsigned int* __restrict__ y2b) {
    __shared__ float Ws[16 * 32];
    __shared__ float bsh[32];
    const int tid = threadIdx.x;
    for (int i = tid; i < 16 * 32; i += 256) Ws[i] = W2[i];
    if (tid < 32) bsh[tid] = b2[tid];
    const int vbase = blockIdx.x * 128;
    const int vl = tid >> 1, c = tid & 1;
    const int vg = vbase + vl;
    const uint4* y4 = (const uint4*)y1h;
    int beg = off[vg], end = off[vg + 1];
    uint4 us = y4[(size_t)vg * 2 + c];   // self half-row
    float a0 = h_lo(us.x), a1 = h_hi(us.x), a2 = h_lo(us.y), a3 = h_hi(us.y),
          a4 = h_lo(us.z), a5 = h_hi(us.z), a6 = h_lo(us.w), a7 = h_hi(us.w);
    float c0 = 0, c1 = 0, c2 = 0, c3 = 0, c4 = 0, c5 = 0, c6 = 0, c7 = 0;
    int e = beg;
    for (; e + 8 <= end; e += 8) {
        int s0 = adj[e], s1 = adj[e + 1], s2 = adj[e + 2], s3 = adj[e + 3];
        int s4 = adj[e + 4], s5 = adj[e + 5], s6 = adj[e + 6], s7 = adj[e + 7];
        uint4 u0 = y4[(size_t)s0 * 2 + c], u1 = y4[(size_t)s1 * 2 + c];
        uint4 u2 = y4[(size_t)s2 * 2 + c], u3 = y4[(size_t)s3 * 2 + c];
        uint4 u4 = y4[(size_t)s4 * 2 + c], u5 = y4[(size_t)s5 * 2 + c];
        uint4 u6 = y4[(size_t)s6 * 2 + c], u7 = y4[(size_t)s7 * 2 + c];
        UNPK8_ADD(a, u0) UNPK8_ADD(c, u1) UNPK8_ADD(a, u2) UNPK8_ADD(c, u3)
        UNPK8_ADD(a, u4) UNPK8_ADD(c, u5) UNPK8_ADD(a, u6) UNPK8_ADD(c, u7)
    }
    for (; e + 2 <= end; e += 2) {
        int s0 = adj[e], s1 = adj[e + 1];
        uint4 u0 = y4[(size_t)s0 * 2 + c], u1 = y4[(size_t)s1 * 2 + c];
        UNPK8_ADD(a, u0) UNPK8_ADD(c, u1)
    }
    if (e < end) {
        uint4 u0 = y4[(size_t)adj[e] * 2 + c];
        UNPK8_ADD(a, u0)
    }
    float dv = dinv[vg];
    float own[8];
    own[0] = (a0 + c0) * dv; own[1] = (a1 + c1) * dv;
    own[2] = (a2 + c2) * dv; own[3] = (a3 + c3) * dv;
    own[4] = (a4 + c4) * dv; own[5] = (a5 + c5) * dv;
    own[6] = (a6 + c6) * dv; own[7] = (a7 + c7) * dv;
    // exchange halves: lane c holds dims [c*8, c*8+8); partner has the rest
    float oth[8];
#pragma unroll
    for (int k = 0; k < 8; k++) oth[k] = __shfl_xor(own[k], 1);
    float in[16];
#pragma unroll
    for (int k = 0; k < 8; k++) {
        in[c * 8 + k] = own[k];
        in[(1 - c) * 8 + k] = oth[k];
    }
    __syncthreads();   // Ws/bsh visibility
    // transform: lane c -> outputs j0 = c*16 .. +15; Ws row pitch 32 floats
    const int j0 = c * 16;
    const float4* W4 = (const float4*)Ws;   // 8 float4 per k-row
    float o[16];
#pragma unroll
    for (int jj = 0; jj < 16; jj += 4) {
        float4 bv = *(const float4*)&bsh[j0 + jj];
        o[jj] = bv.x; o[jj + 1] = bv.y; o[jj + 2] = bv.z; o[jj + 3] = bv.w;
    }
#pragma unroll
    for (int k = 0; k < 16; k++) {
        float xk = in[k];
        float4 w0 = W4[k * 8 + c * 4 + 0], w1 = W4[k * 8 + c * 4 + 1];
        float4 w2 = W4[k * 8 + c * 4 + 2], w3 = W4[k * 8 + c * 4 + 3];
        o[0] = fmaf(xk, w0.x, o[0]);  o[1] = fmaf(xk, w0.y, o[1]);
        o[2] = fmaf(xk, w0.z, o[2]);  o[3] = fmaf(xk, w0.w, o[3]);
        o[4] = fmaf(xk, w1.x, o[4]);  o[5] = fmaf(xk, w1.y, o[5]);
        o[6] = fmaf(xk, w1.z, o[6]);  o[7] = fmaf(xk, w1.w, o[7]);
        o[8] = fmaf(xk, w2.x, o[8]);  o[9] = fmaf(xk, w2.y, o[9]);
        o[10] = fmaf(xk, w2.z, o[10]); o[11] = fmaf(xk, w2.w, o[11]);
        o[12] = fmaf(xk, w3.x, o[12]); o[13] = fmaf(xk, w3.y, o[13]);
        o[14] = fmaf(xk, w3.z, o[14]); o[15] = fmaf(xk, w3.w, o[15]);
    }
    uint4 p0, p1;
    p0.x = pkh(dv * fmaxf(o[0], 0.f),  dv * fmaxf(o[1], 0.f));
    p0.y = pkh(dv * fmaxf(o[2], 0.f),  dv * fmaxf(o[3], 0.f));
    p0.z = pkh(dv * fmaxf(o[4], 0.f),  dv * fmaxf(o[5], 0.f));
    p0.w = pkh(dv * fmaxf(o[6], 0.f),  dv * fmaxf(o[7], 0.f));
    p1.x = pkh(dv * fmaxf(o[8], 0.f),  dv * fmaxf(o[9], 0.f));
    p1.y = pkh(dv * fmaxf(o[10], 0.f), dv * fmaxf(o[11], 0.f));
    p1.z = pkh(dv * fmaxf(o[12], 0.f), dv * fmaxf(o[13], 0.f));
    p1.w = pkh(dv * fmaxf(o[14], 0.f), dv * fmaxf(o[15], 0.f));
    uint4* out4 = (uint4*)y2b;
    out4[(size_t)vg * 4 + c * 2]     = p0;
    out4[(size_t)vg * 4 + c * 2 + 1] = p1;
}

// ---- agg(32-dim, fp16 rows) -> fp16 a3 -------------------------------------
// 4 lanes/node, each lane one uint4 (8 fp16) chunk; R13: 4-wide unroll.
__global__ void __launch_bounds__(256)
agg3_kernel(const unsigned int* __restrict__ y2b, const int* __restrict__ off,
            const int* __restrict__ adj, const float* __restrict__ dinv,
            _Float16* __restrict__ a3out, int n) {
    int t = blockIdx.x * 256 + threadIdx.x;
    int v = t >> 2, c = t & 3;
    if (v >= n) return;
    const uint4* yb = (const uint4*)y2b;
    uint4 us = yb[(size_t)v * 4 + c];   // self
    float a0 = h_lo(us.x), a1 = h_hi(us.x), a2 = h_lo(us.y), a3 = h_hi(us.y),
          a4 = h_lo(us.z), a5 = h_hi(us.z), a6 = h_lo(us.w), a7 = h_hi(us.w);
    float c0 = 0, c1 = 0, c2 = 0, c3 = 0, c4 = 0, c5 = 0, c6 = 0, c7 = 0;
    int beg = off[v], end = off[v + 1];
    int e = beg;
    for (; e + 4 <= end; e += 4) {
        int s0 = adj[e], s1 = adj[e + 1], s2 = adj[e + 2], s3 = adj[e + 3];
        uint4 u0 = yb[(size_t)s0 * 4 + c];
        uint4 u1 = yb[(size_t)s1 * 4 + c];
        uint4 u2 = yb[(size_t)s2 * 4 + c];
        uint4 u3 = yb[(size_t)s3 * 4 + c];
        UNPK8_ADD(a, u0) UNPK8_ADD(c, u1) UNPK8_ADD(a, u2) UNPK8_ADD(c, u3)
    }
    for (; e + 2 <= end; e += 2) {
        int s0 = adj[e], s1 = adj[e + 1];
        uint4 u0 = yb[(size_t)s0 * 4 + c];
        uint4 u1 = yb[(size_t)s1 * 4 + c];
        UNPK8_ADD(a, u0) UNPK8_ADD(c, u1)
    }
    if (e < end) {
        uint4 u0 = yb[(size_t)adj[e] * 4 + c];
        UNPK8_ADD(a, u0)
    }
    float dv = dinv[v];
    uint4 st;
    st.x = pkh((a0 + c0) * dv, (a1 + c1) * dv);
    st.y = pkh((a2 + c2) * dv, (a3 + c3) * dv);
    st.z = pkh((a4 + c4) * dv, (a5 + c5) * dv);
    st.w = pkh((a6 + c6) * dv, (a7 + c7) * dv);
    ((uint4*)a3out)[(size_t)v * 4 + c] = st;
}

// ---- Fused layer-3 transform + FC via MFMA ---------------------------------
// 256 threads = 4 waves, 64 nodes/block (16 per wave).  No __syncthreads:
// B-frags come straight from global (frag-ordered fp16, L1-hot), the only
// LDS is a per-wave 2KB frag-ordered relu(t) scratch (contiguous 16B/lane
// reads -> conflict-free).  Intra-wave LDS dep: compiler-inserted lgkmcnt.
__global__ void __launch_bounds__(256)
t3fc_kernel(const _Float16* __restrict__ a3h,
            const _Float16* __restrict__ w3f, const float* __restrict__ b3,
            const _Float16* __restrict__ wff, const float* __restrict__ bf,
            float* __restrict__ out) {
    __shared__ __align__(16) _Float16 tA[4][1024];   // [wave][ks*512 + row*32 + h*8 + e]
    const int tid = threadIdx.x;
    const int w = tid >> 6, l = tid & 63;
    const int lr = l & 15, lh = l >> 4;
    const int vbase = blockIdx.x * 64 + w * 16;
    const int fragoff = lr * 32 + lh * 8;

    // A1: node row = vbase+lr, k = lh*8..lh*8+7 (fp16, 16B/lane)
    half8 A1 = *(const half8*)(a3h + (size_t)(vbase + lr) * 32 + lh * 8);

    // GEMM1: 4 col-tiles, K=32 in one MFMA each
    float4v c1[4];
#pragma unroll
    for (int nt = 0; nt < 4; nt++) {
        float bv = b3[nt * 16 + lr];                  // D col = nt*16+lr
        float4v ci = {bv, bv, bv, bv};
        half8 B = *(const half8*)(w3f + nt * 512 + fragoff);
        c1[nt] = __builtin_amdgcn_mfma_f32_16x16x32_f16(A1, B, ci, 0, 0, 0);
    }

    // relu -> fp16 -> per-wave frag-ordered scratch.
    // D elem (row = lh*4+r, col = nt*16+lr) becomes t[row][k2=col]:
    //   idx = (k2>>5)*512 + row*32 + ((k2>>3)&3)*8 + (k2&7)
    _Float16* tw = tA[w];
#pragma unroll
    for (int nt = 0; nt < 4; nt++) {
        int k2 = nt * 16 + lr;
        int base = (k2 >> 5) * 512 + ((k2 >> 3) & 3) * 8 + (k2 & 7);
#pragma unroll
        for (int r = 0; r < 4; r++)
            tw[base + (lh * 4 + r) * 32] = (_Float16)fmaxf(c1[nt][r], 0.f);
    }

    // GEMM2: K=64 = 2 k-steps x 4 col-tiles
    float4v c2[4];
#pragma unroll
    for (int nt = 0; nt < 4; nt++) {
        float bv = bf[nt * 16 + lr];
        c2[nt] = (float4v){bv, bv, bv, bv};
    }
#pragma unroll
    for (int ks = 0; ks < 2; ks++) {
        half8 A2 = *(const half8*)(tw + ks * 512 + fragoff);
#pragma unroll
        for (int nt = 0; nt < 4; nt++) {
            half8 B = *(const half8*)(wff + (ks * 4 + nt) * 512 + fragoff);
            c2[nt] = __builtin_amdgcn_mfma_f32_16x16x32_f16(A2, B, c2[nt], 0, 0, 0);
        }
    }

    // store: D elem (row = lh*4+r, col = nt*16+lr); 64B segments per (nt,r)
#pragma unroll
    for (int nt = 0; nt < 4; nt++) {
#pragma unroll
        for (int r = 0; r < 4; r++)
            out[(size_t)(vbase + lh * 4 + r) * 64 + nt * 16 + lr] = c2[nt][r];
    }
}

extern "C" void kernel_launch(void* const* d_in, const int* in_sizes, int n_in,
                              void* d_out, int out_size, void* d_ws, size_t ws_size,
                              hipStream_t stream) {
    const float* x  = (const float*)d_in[0];
    const float* W1 = (const float*)d_in[1];
    const float* b1 = (const float*)d_in[2];
    const float* W2 = (const float*)d_in[3];
    const float* b2 = (const float*)d_in[4];
    const float* W3 = (const float*)d_in[5];
    const float* b3 = (const float*)d_in[6];
    const float* Wf = (const float*)d_in[7];
    const float* bf = (const float*)d_in[8];
    const int*   ei = (const int*)d_in[9];

    const int N = in_sizes[0] / 8;   // 262144
    const int E = in_sizes[9] / 2;   // 2097152
    const int* srcv = ei;
    const int* dstv = ei + E;
    const int shift = 10;            // log2(NPB)

    // Workspace layout (16B-aligned chunks)
    char* p = (char*)d_ws;
    auto take = [&p](size_t bytes) { char* q = p; p += (bytes + 63) & ~size_t(63); return q; };
    int*   off   = (int*)take((size_t)(N + 16) * 4);
    float* dinv  = (float*)take((size_t)N * 4);
    int*   adj   = (int*)take((size_t)E * 4);
    int*   ghist = (int*)take(NB * 4);
    int*   bbase = (int*)take((NB + 1) * 4);
    int*   gcur  = (int*)take(NB * 4);
    _Float16* w3f = (_Float16*)take(32 * 64 * 2);      // frag-ordered fp16 W3
    _Float16* wff = (_Float16*)take(64 * 64 * 2);      // frag-ordered fp16 Wf
    char*  bufA  = take((size_t)N * 32 * 4);           // y0h (4MB) then a3h (fp16, 16MB)
    char*  bufB  = take((size_t)N * 16 * 4);           // y1h (fp16, 8MB)
    char*  regX  = take((size_t)N * 32 * 2);           // 16MB: bedge (8MB) then y2b (fp16)
    unsigned int* bedge = (unsigned int*)regX;
    unsigned int* y2b   = (unsigned int*)regX;
    _Float16* y0h = (_Float16*)bufA;
    _Float16* a3h = (_Float16*)bufA;
    _Float16* y1h = (_Float16*)bufB;

    hipMemsetAsync(ghist, 0, NB * 4, stream);

    int nt = (E + TILE - 1) / TILE;  // 512 tiles
    hist_kernel<<<nt, 256, 0, stream>>>(dstv, ghist, E, shift);
    bscan_kernel<<<1, NB, 0, stream>>>(ghist, bbase, gcur, W3, Wf, w3f, wff);
    partition_kernel<<<nt, 256, 0, stream>>>(srcv, dstv, gcur, bedge, E, shift, NPB - 1);
    build_kernel<<<NB, 256, 0, stream>>>(bbase, bedge, x, off, dinv, adj, y0h);

    // L1: agg(y0h) + transform 8->16 -> y1h (fp16)
    aggt1_kernel<<<N / 256, 256, 0, stream>>>(y0h, off, adj, dinv, W1, b1, y1h);
    // L2: agg(y1h) + transform 16->32 -> y2b (fp16; overwrites dead bedge)
    aggt2_kernel<<<N / 128, 256, 0, stream>>>(y1h, off, adj, dinv, W2, b2, y2b);
    // L3: agg(y2b) -> a3h (fp16, in bufA; y0h dead), then MFMA transform+FC -> out
    agg3_kernel<<<(N * 4) / 256, 256, 0, stream>>>(y2b, off, adj, dinv, a3h, N);
    t3fc_kernel<<<N / 64, 256, 0, stream>>>(a3h, w3f, b3, wff, bf, (float*)d_out);
}